// Round 2
// baseline (3360.094 us; speedup 1.0000x reference)
//
#include <hip/hip_runtime.h>

typedef unsigned int uint;

#define NB 16
#define NN 4096
#define NS 1024
#define NK 32
#define CIN0 67
#define NPTS (NB*NS*NK)           // 524288
#define BN_EPS 1e-5f
#define INV_NPTS (1.0f/524288.0f) // exact power of two

// transposed-weight offsets inside wT (floats)
#define W0T_OFF 0      // [67][64]  = 4288
#define W1T_OFF 4288   // [64][64]  = 4096
#define W2T_OFF 8384   // [64][128] = 8192
#define WT_TOTAL 16576

// ---------------------------------------------------------------- FPS
// One block per batch. Mirrors: d = ((dx*dx + dy*dy) + dz*dz), contract off.
// argmax with first-occurrence tie-break (smaller index wins on equality).
#define FPS_T 512
#define PPT (NN / FPS_T) // 8

__global__ __launch_bounds__(FPS_T) void fps_kernel(
    const float* __restrict__ xyz, float* __restrict__ centers,
    float* __restrict__ out_newxyz)
{
#pragma clang fp contract(off)
  __shared__ float sx[NN], sy[NN], sz[NN];
  __shared__ int sfar[NS];
  __shared__ float redv[2][FPS_T/64];
  __shared__ int   redi[2][FPS_T/64];
  const int b = blockIdx.x;
  const int tid = threadIdx.x;
  const float* xb = xyz + (size_t)b * NN * 3;
  for (int i = tid; i < NN; i += FPS_T) {
    sx[i] = xb[i*3+0]; sy[i] = xb[i*3+1]; sz[i] = xb[i*3+2];
  }
  __syncthreads();
  float px[PPT], py[PPT], pz[PPT], dist[PPT];
  const int base = tid * PPT;
#pragma unroll
  for (int j = 0; j < PPT; ++j) {
    px[j] = sx[base+j]; py[j] = sy[base+j]; pz[j] = sz[base+j];
    dist[j] = 1e10f;
  }
  float cx = sx[0], cy = sy[0], cz = sz[0];
  if (tid == 0) sfar[0] = 0;

  for (int it = 1; it < NS; ++it) {
    float bv = -1.0f; int bi = 0x7fffffff;
#pragma unroll
    for (int j = 0; j < PPT; ++j) {
      float dx = px[j]-cx, dy = py[j]-cy, dz = pz[j]-cz;
      float d = (dx*dx + dy*dy) + dz*dz;
      float dd = dist[j];
      dd = d < dd ? d : dd;
      dist[j] = dd;
      if (dd > bv) { bv = dd; bi = base + j; }
    }
#pragma unroll
    for (int m = 1; m < 64; m <<= 1) {
      float ov = __shfl_xor(bv, m);
      int   oi = __shfl_xor(bi, m);
      if (ov > bv || (ov == bv && oi < bi)) { bv = ov; bi = oi; }
    }
    const int pb = it & 1;
    if ((tid & 63) == 0) { redv[pb][tid>>6] = bv; redi[pb][tid>>6] = bi; }
    __syncthreads();
    float fv = redv[pb][0]; int fi = redi[pb][0];
#pragma unroll
    for (int w = 1; w < FPS_T/64; ++w) {
      float ov = redv[pb][w]; int oi = redi[pb][w];
      if (ov > fv || (ov == fv && oi < fi)) { fv = ov; fi = oi; }
    }
    cx = sx[fi]; cy = sy[fi]; cz = sz[fi];
    if (tid == 0) sfar[it] = fi;
  }
  __syncthreads();
  for (int s = tid; s < NS; s += FPS_T) {
    int f = sfar[s];
    float x = sx[f], y = sy[f], z = sz[f];
    size_t o = ((size_t)b * NS + s) * 3;
    centers[o] = x; centers[o+1] = y; centers[o+2] = z;
    out_newxyz[o] = x; out_newxyz[o+1] = y; out_newxyz[o+2] = z;
  }
}

// ---------------------------------------------------------------- ball query
__global__ __launch_bounds__(64) void ball_kernel(
    const float* __restrict__ xyz, const float* __restrict__ centers,
    int* __restrict__ group_idx)
{
#pragma clang fp contract(off)
  __shared__ float sx[NN], sy[NN], sz[NN];
  const int bid = blockIdx.x;       // 256 blocks: 16 per batch
  const int b = bid >> 4;
  const int s = ((bid & 15) << 6) + threadIdx.x;
  const float* xb = xyz + (size_t)b * NN * 3;
  for (int i = threadIdx.x; i < NN; i += 64) {
    sx[i] = xb[i*3+0]; sy[i] = xb[i*3+1]; sz[i] = xb[i*3+2];
  }
  __syncthreads();
  const size_t co = ((size_t)b * NS + s) * 3;
  const float cx = centers[co], cy = centers[co+1], cz = centers[co+2];
  const float csq = (cx*cx + cy*cy) + cz*cz;
  int* out = group_idx + ((size_t)b * NS + s) * NK;
  int count = 0, first = 0;
  for (int i = 0; i < NN; ++i) {
    const float x = sx[i], y = sy[i], z = sz[i];
    const float psq = (x*x + y*y) + z*z;
    const float dot = (cx*x + cy*y) + cz*z;
    const float dist = (csq + psq) - 2.0f*dot;
    if (dist <= 0.25f) {
      if (count == 0) first = i;
      if (count < NK) out[count] = i;
      count++;
    }
    if ((i & 63) == 63) {
      if (!__any(count < NK)) break;
    }
  }
  for (int r = count; r < NK; ++r) out[r] = first;
}

// ---------------------------------------------------------------- weight transpose prep
__global__ __launch_bounds__(256) void prep_kernel(
    const float* __restrict__ w0, const float* __restrict__ w1,
    const float* __restrict__ w2, float* __restrict__ wT)
{
  int i = blockIdx.x*256 + threadIdx.x;
  if (i < 4288) {
    int c = i >> 6, d = i & 63;
    wT[i] = w0[d*CIN0 + c];
  } else if (i < 8384) {
    int j = i - 4288; int c = j >> 6, d = j & 63;
    wT[i] = w1[d*64 + c];
  } else if (i < WT_TOTAL) {
    int j = i - 8384; int c = j >> 7, d = j & 127;
    wT[i] = w2[d*64 + c];
  }
}

// ---------------------------------------------------------------- device helpers
__device__ __forceinline__ float gelu_exact(float x) {
  return (0.5f * x) * (erff(x * 0.70710678118654752f) + 1.0f);
}

__device__ __forceinline__ void fmac64(float (&acc)[64], const float* wrow, float xc) {
  const float4* wp = (const float4*)wrow;
#pragma unroll
  for (int i = 0; i < 16; ++i) {
    float4 w = wp[i];
    acc[i*4+0] = fmaf(xc, w.x, acc[i*4+0]);
    acc[i*4+1] = fmaf(xc, w.y, acc[i*4+1]);
    acc[i*4+2] = fmaf(xc, w.z, acc[i*4+2]);
    acc[i*4+3] = fmaf(xc, w.w, acc[i*4+3]);
  }
}

// layer0 for point p into acc[64]; wsh = W0T [67][64] in LDS; b0v in LDS
__device__ __forceinline__ void layer0(
    const float* __restrict__ xyz, const float* __restrict__ feat,
    const float* __restrict__ centers, const int* __restrict__ gidx,
    const float* wsh, const float* b0v, int p, float (&acc)[64])
{
  const int b = p >> 15;
  const int s = (p & 32767) >> 5;
  const int gi = gidx[p];
#pragma unroll
  for (int d = 0; d < 64; ++d) acc[d] = b0v[d];
  const float* cp = centers + ((size_t)(b*NS + s))*3;
  const float* pp = xyz + ((size_t)(b*NN) + gi)*3;
  fmac64(acc, wsh + 0*64, pp[0]-cp[0]);
  fmac64(acc, wsh + 1*64, pp[1]-cp[1]);
  fmac64(acc, wsh + 2*64, pp[2]-cp[2]);
  const float4* fr = (const float4*)(feat + ((size_t)(b*NN) + gi)*64);
#pragma unroll 2
  for (int q = 0; q < 16; ++q) {
    float4 v = fr[q];
    fmac64(acc, wsh + (3+q*4)*64, v.x);
    fmac64(acc, wsh + (4+q*4)*64, v.y);
    fmac64(acc, wsh + (5+q*4)*64, v.z);
    fmac64(acc, wsh + (6+q*4)*64, v.w);
  }
}

// per-channel block column-sums of v into bsum/bssq (LDS, unique owner per
// channel). Uses sbuf[4352] with barriers; ends with a barrier.
__device__ __forceinline__ void block_colsum64(const float (&v)[64], float* sbuf,
    float* bsum, float* bssq, int cbase)
{
  const int tid = threadIdx.x;
#pragma unroll
  for (int cc = 0; cc < 4; ++cc) {
    __syncthreads();
#pragma unroll
    for (int j = 0; j < 16; ++j) sbuf[tid*17 + j] = v[cc*16 + j];
    __syncthreads();
    const int c = tid & 15, seg = tid >> 4;
    float s = 0.f, q = 0.f;
#pragma unroll
    for (int i = 0; i < 16; ++i) {
      float x = sbuf[(seg*16 + i)*17 + c];
      s += x; q += x*x;
    }
    __syncthreads();
    sbuf[tid*2] = s; sbuf[tid*2+1] = q;
    __syncthreads();
    if (tid < 16) {
      float ss = 0.f, qq = 0.f;
#pragma unroll
      for (int sg = 0; sg < 16; ++sg) {
        ss += sbuf[(sg*16 + tid)*2];
        qq += sbuf[(sg*16 + tid)*2 + 1];
      }
      bsum[cbase + cc*16 + tid] += ss;
      bssq[cbase + cc*16 + tid] += qq;
    }
  }
  __syncthreads();
}

// chain up to x2 = gelu(bn1(W1 gelu(bn0(W0 x + b0)) + b1)).
// wsh: W0T at 0, W1T at 4288. sbuf row tid*17 used for dynamic-index staging.
// prm: 0 b0 | 64 sc0 | 128 sh0 | 192 b1 | 256 sc1 | 320 sh1
__device__ __forceinline__ void chain_to_x2(
    const float* __restrict__ xyz, const float* __restrict__ feat,
    const float* __restrict__ centers, const int* __restrict__ gidx,
    const float* wsh, float* sbuf, const float* prm, int p, float (&x2)[64])
{
  float acc0[64];
  layer0(xyz, feat, centers, gidx, wsh, prm, p, acc0);
#pragma unroll
  for (int c = 0; c < 64; ++c) acc0[c] = gelu_exact(fmaf(acc0[c], prm[64+c], prm[128+c]));
#pragma unroll
  for (int d = 0; d < 64; ++d) x2[d] = prm[192+d];
  float* xrow = sbuf + threadIdx.x*17;
#pragma unroll
  for (int cc = 0; cc < 4; ++cc) {
#pragma unroll
    for (int j = 0; j < 16; ++j) xrow[j] = acc0[cc*16 + j];
#pragma unroll 1
    for (int cj = 0; cj < 16; ++cj)
      fmac64(x2, wsh + W1T_OFF + (cc*16+cj)*64, xrow[cj]);
  }
#pragma unroll
  for (int c = 0; c < 64; ++c) x2[c] = gelu_exact(fmaf(x2[c], prm[256+c], prm[320+c]));
}

// ---------------------------------------------------------------- S0: h0 stats
__global__ __launch_bounds__(256,2) void s0_kernel(
    const float* __restrict__ xyz, const float* __restrict__ feat,
    const float* __restrict__ centers, const int* __restrict__ gidx,
    const float* __restrict__ wT, const float* __restrict__ b0,
    float* __restrict__ stat0)
{
  __shared__ float wsh[4288];
  __shared__ float sbuf[4352];
  __shared__ float bsum[64], bssq[64], b0s[64];
  const int tid = threadIdx.x;
  for (int i = tid; i < 1072; i += 256) ((float4*)wsh)[i] = ((const float4*)wT)[i];
  if (tid < 64) { bsum[tid] = 0.f; bssq[tid] = 0.f; b0s[tid] = b0[tid]; }
  __syncthreads();
  const int p = blockIdx.x*256 + tid;
  float acc[64];
  layer0(xyz, feat, centers, gidx, wsh, b0s, p, acc);
  block_colsum64(acc, sbuf, bsum, bssq, 0);
  if (tid < 64) {
    atomicAdd(&stat0[tid], bsum[tid]);
    atomicAdd(&stat0[64+tid], bssq[tid]);
  }
}

// ---------------------------------------------------------------- S1: h1 stats
__global__ __launch_bounds__(256,2) void s1_kernel(
    const float* __restrict__ xyz, const float* __restrict__ feat,
    const float* __restrict__ centers, const int* __restrict__ gidx,
    const float* __restrict__ wT, const float* __restrict__ stat0,
    const float* __restrict__ g0, const float* __restrict__ be0,
    const float* __restrict__ b0, const float* __restrict__ b1,
    float* __restrict__ stat1)
{
  __shared__ float wsh[8384];
  __shared__ float sbuf[4352];
  __shared__ float bsum[64], bssq[64];
  __shared__ float prm[256];
  const int tid = threadIdx.x;
  for (int i = tid; i < 2096; i += 256) ((float4*)wsh)[i] = ((const float4*)wT)[i];
  if (tid < 64) {
    float m0 = stat0[tid]*INV_NPTS;
    float v0 = stat0[64+tid]*INV_NPTS - m0*m0;
    float sc0 = (1.0f/sqrtf(v0 + BN_EPS)) * g0[tid];
    prm[tid] = b0[tid]; prm[64+tid] = sc0; prm[128+tid] = be0[tid] - m0*sc0;
    prm[192+tid] = b1[tid];
    bsum[tid] = 0.f; bssq[tid] = 0.f;
  }
  __syncthreads();
  const int p = blockIdx.x*256 + tid;
  float acc0[64];
  layer0(xyz, feat, centers, gidx, wsh, prm, p, acc0);
#pragma unroll
  for (int c = 0; c < 64; ++c) acc0[c] = gelu_exact(fmaf(acc0[c], prm[64+c], prm[128+c]));
  float acc1[64];
#pragma unroll
  for (int d = 0; d < 64; ++d) acc1[d] = prm[192+d];
  float* xrow = sbuf + tid*17;
#pragma unroll
  for (int cc = 0; cc < 4; ++cc) {
#pragma unroll
    for (int j = 0; j < 16; ++j) xrow[j] = acc0[cc*16 + j];
#pragma unroll 1
    for (int cj = 0; cj < 16; ++cj)
      fmac64(acc1, wsh + W1T_OFF + (cc*16+cj)*64, xrow[cj]);
  }
  block_colsum64(acc1, sbuf, bsum, bssq, 0);
  if (tid < 64) {
    atomicAdd(&stat1[tid], bsum[tid]);
    atomicAdd(&stat1[64+tid], bssq[tid]);
  }
}

// ---------------------------------------------------------------- S2: h2 stats
__global__ __launch_bounds__(256,2) void s2_kernel(
    const float* __restrict__ xyz, const float* __restrict__ feat,
    const float* __restrict__ centers, const int* __restrict__ gidx,
    const float* __restrict__ wT,
    const float* __restrict__ stat0, const float* __restrict__ g0,
    const float* __restrict__ be0, const float* __restrict__ b0,
    const float* __restrict__ b1, const float* __restrict__ stat1,
    const float* __restrict__ g1, const float* __restrict__ be1,
    const float* __restrict__ b2, float* __restrict__ stat2)
{
  __shared__ float wsh[8384];
  __shared__ float sbuf[4352];
  __shared__ float bsum[128], bssq[128];
  __shared__ float prm[512];
  const int tid = threadIdx.x;
  for (int i = tid; i < 2096; i += 256) ((float4*)wsh)[i] = ((const float4*)wT)[i];
  if (tid < 64) {
    float m0 = stat0[tid]*INV_NPTS;
    float v0 = stat0[64+tid]*INV_NPTS - m0*m0;
    float sc0 = (1.0f/sqrtf(v0 + BN_EPS)) * g0[tid];
    prm[tid] = b0[tid]; prm[64+tid] = sc0; prm[128+tid] = be0[tid] - m0*sc0;
    float m1 = stat1[tid]*INV_NPTS;
    float v1 = stat1[64+tid]*INV_NPTS - m1*m1;
    float sc1 = (1.0f/sqrtf(v1 + BN_EPS)) * g1[tid];
    prm[192+tid] = b1[tid]; prm[256+tid] = sc1; prm[320+tid] = be1[tid] - m1*sc1;
  }
  if (tid < 128) { prm[384+tid] = b2[tid]; bsum[tid] = 0.f; bssq[tid] = 0.f; }
  __syncthreads();
  const int p = blockIdx.x*256 + tid;
  float x2[64];
  chain_to_x2(xyz, feat, centers, gidx, wsh, sbuf, prm, p, x2);
  __syncthreads();                       // done with W0/W1
  for (int i = tid; i < 2048; i += 256)
    ((float4*)wsh)[i] = ((const float4*)(wT + W2T_OFF))[i];
  __syncthreads();
  float* xrow = sbuf + tid*17;
#pragma unroll 1
  for (int half = 0; half < 2; ++half) {
    float a2[64];
#pragma unroll
    for (int d = 0; d < 64; ++d) a2[d] = prm[384 + half*64 + d];
#pragma unroll
    for (int cc = 0; cc < 4; ++cc) {
#pragma unroll
      for (int j = 0; j < 16; ++j) xrow[j] = x2[cc*16 + j];
#pragma unroll 1
      for (int cj = 0; cj < 16; ++cj)
        fmac64(a2, wsh + (cc*16+cj)*128 + half*64, xrow[cj]);
    }
    block_colsum64(a2, sbuf, bsum, bssq, half*64);
  }
  if (tid < 128) {
    atomicAdd(&stat2[tid], bsum[tid]);
    atomicAdd(&stat2[128+tid], bssq[tid]);
  }
}

// ---------------------------------------------------------------- F: chain + bn2 + gelu + maxpool
__global__ __launch_bounds__(256,2) void fin_kernel(
    const float* __restrict__ xyz, const float* __restrict__ feat,
    const float* __restrict__ centers, const int* __restrict__ gidx,
    const float* __restrict__ wT,
    const float* __restrict__ stat0, const float* __restrict__ g0,
    const float* __restrict__ be0, const float* __restrict__ b0,
    const float* __restrict__ b1, const float* __restrict__ stat1,
    const float* __restrict__ g1, const float* __restrict__ be1,
    const float* __restrict__ b2, const float* __restrict__ stat2,
    const float* __restrict__ g2, const float* __restrict__ be2,
    float* __restrict__ out_feat)
{
  __shared__ float wsh[8384];
  __shared__ float sbuf[4352];
  __shared__ float prm[768];
  const int tid = threadIdx.x;
  for (int i = tid; i < 2096; i += 256) ((float4*)wsh)[i] = ((const float4*)wT)[i];
  if (tid < 64) {
    float m0 = stat0[tid]*INV_NPTS;
    float v0 = stat0[64+tid]*INV_NPTS - m0*m0;
    float sc0 = (1.0f/sqrtf(v0 + BN_EPS)) * g0[tid];
    prm[tid] = b0[tid]; prm[64+tid] = sc0; prm[128+tid] = be0[tid] - m0*sc0;
    float m1 = stat1[tid]*INV_NPTS;
    float v1 = stat1[64+tid]*INV_NPTS - m1*m1;
    float sc1 = (1.0f/sqrtf(v1 + BN_EPS)) * g1[tid];
    prm[192+tid] = b1[tid]; prm[256+tid] = sc1; prm[320+tid] = be1[tid] - m1*sc1;
  }
  if (tid < 128) {
    prm[384+tid] = b2[tid];
    float m2 = stat2[tid]*INV_NPTS;
    float v2 = stat2[128+tid]*INV_NPTS - m2*m2;
    float sc2 = (1.0f/sqrtf(v2 + BN_EPS)) * g2[tid];
    prm[512+tid] = sc2; prm[640+tid] = be2[tid] - m2*sc2;
  }
  __syncthreads();
  const int p = blockIdx.x*256 + tid;
  const int b = p >> 15;
  const int s = (p & 32767) >> 5;
  float x2[64];
  chain_to_x2(xyz, feat, centers, gidx, wsh, sbuf, prm, p, x2);
  __syncthreads();                       // done with W0/W1
  for (int i = tid; i < 2048; i += 256)
    ((float4*)wsh)[i] = ((const float4*)(wT + W2T_OFF))[i];
  __syncthreads();
  float* xrow = sbuf + tid*17;
#pragma unroll 1
  for (int half = 0; half < 2; ++half) {
    float a2[64];
#pragma unroll
    for (int d = 0; d < 64; ++d) a2[d] = prm[384 + half*64 + d];
#pragma unroll
    for (int cc = 0; cc < 4; ++cc) {
#pragma unroll
      for (int j = 0; j < 16; ++j) xrow[j] = x2[cc*16 + j];
#pragma unroll 1
      for (int cj = 0; cj < 16; ++cj)
        fmac64(a2, wsh + (cc*16+cj)*128 + half*64, xrow[cj]);
    }
    // bn2 + gelu + maxpool over the 32 lanes of this (b,s) group
#pragma unroll
    for (int d = 0; d < 64; ++d) {
      float y = gelu_exact(fmaf(a2[d], prm[512 + half*64 + d], prm[640 + half*64 + d]));
#pragma unroll
      for (int m = 1; m < 32; m <<= 1) y = fmaxf(y, __shfl_xor(y, m));
      a2[d] = y;
    }
    if ((tid & 31) == 0) {
      float4* op = (float4*)(out_feat + ((size_t)(b*NS + s))*128 + half*64);
#pragma unroll
      for (int i = 0; i < 16; ++i)
        op[i] = make_float4(a2[i*4], a2[i*4+1], a2[i*4+2], a2[i*4+3]);
    }
  }
}

// ---------------------------------------------------------------- launch
extern "C" void kernel_launch(void* const* d_in, const int* in_sizes, int n_in,
                              void* d_out, int out_size, void* d_ws, size_t ws_size,
                              hipStream_t stream) {
  (void)in_sizes; (void)n_in; (void)out_size;
  const float* xyz      = (const float*)d_in[0];
  const float* features = (const float*)d_in[1];
  const float* w0  = (const float*)d_in[2];
  const float* b0  = (const float*)d_in[3];
  const float* g0  = (const float*)d_in[4];
  const float* be0 = (const float*)d_in[5];
  const float* w1  = (const float*)d_in[6];
  const float* b1  = (const float*)d_in[7];
  const float* g1  = (const float*)d_in[8];
  const float* be1 = (const float*)d_in[9];
  const float* w2  = (const float*)d_in[10];
  const float* b2  = (const float*)d_in[11];
  const float* g2  = (const float*)d_in[12];
  const float* be2 = (const float*)d_in[13];

  float* out = (float*)d_out;
  float* out_newxyz = out;                 // (16,1024,3)
  float* out_feat   = out + NB*NS*3;       // (16,1024,128)

  char* ws = (char*)d_ws;
  size_t off = 0;
  float* centers   = (float*)(ws + off); off += (size_t)NB*NS*3*4;     // 192 KB
  int*   group_idx = (int*)(ws + off);   off += (size_t)NPTS*4;        // 2 MB
  float* stats     = (float*)(ws + off); off += 512*4;                 // 2 KB
  off = (off + 255) & ~(size_t)255;
  float* wT        = (float*)(ws + off); off += (size_t)WT_TOTAL*4;    // 66 KB
  if (ws_size < off) return;  // ~2.4 MB needed

  float* stat0 = stats;        // [sum64 | ssq64]
  float* stat1 = stats + 128;  // [sum64 | ssq64]
  float* stat2 = stats + 256;  // [sum128 | ssq128]

  hipMemsetAsync(stats, 0, 2048, stream);
  prep_kernel<<<65, 256, 0, stream>>>(w0, w1, w2, wT);
  fps_kernel<<<NB, FPS_T, 0, stream>>>(xyz, centers, out_newxyz);
  ball_kernel<<<256, 64, 0, stream>>>(xyz, centers, group_idx);
  s0_kernel<<<NPTS/256, 256, 0, stream>>>(xyz, features, centers, group_idx, wT, b0, stat0);
  s1_kernel<<<NPTS/256, 256, 0, stream>>>(xyz, features, centers, group_idx, wT,
                                          stat0, g0, be0, b0, b1, stat1);
  s2_kernel<<<NPTS/256, 256, 0, stream>>>(xyz, features, centers, group_idx, wT,
                                          stat0, g0, be0, b0, b1, stat1, g1, be1, b2, stat2);
  fin_kernel<<<NPTS/256, 256, 0, stream>>>(xyz, features, centers, group_idx, wT,
                                           stat0, g0, be0, b0, b1, stat1, g1, be1, b2,
                                           stat2, g2, be2, out_feat);
}

// Round 4
// 2327.601 us; speedup vs baseline: 1.4436x; 1.4436x over previous
//
#include <hip/hip_runtime.h>

typedef unsigned int uint;
typedef unsigned short ushort;

#define NB 16
#define NN 4096
#define NS 1024
#define NK 32
#define CIN0 67
#define NPTS (NB*NS*NK)           // 524288
#define BN_EPS 1e-5f
#define INV_NPTS (1.0f/524288.0f) // exact power of two

// transposed-weight offsets inside wT (floats)
#define W0T_OFF 0      // [67][64]  = 4288
#define W1T_OFF 4288   // [64][64]  = 4096
#define W2T_OFF 8384   // [64][128] = 8192
#define WT_TOTAL 16576

// ================================================================ FPS v2
// 256 threads (4 waves), 16 pts/thread. DPP row_ror reduce for intra-row,
// __shfl_xor for xor16/xor32. Argmax semantics: max value, min index on tie
// (associative+commutative -> any reduction shape valid). Mirrors reference
// arithmetic with contract off.
#define FPS_T 256
#define PPT (NN / FPS_T) // 16

__device__ __forceinline__ void amax_merge(float& bv, int& bi, float ov, int oi) {
  if (ov > bv || (ov == bv && oi < bi)) { bv = ov; bi = oi; }
}

// dpp_ctrl literals: row_ror:N = 0x120+N (rotate within 16-lane row)
#define DPP_AMAX_STEP(CTRL) do { \
    int _ov = __builtin_amdgcn_update_dpp(0, __float_as_int(bv), (CTRL), 0xF, 0xF, true); \
    int _oi = __builtin_amdgcn_update_dpp(0, bi,                 (CTRL), 0xF, 0xF, true); \
    amax_merge(bv, bi, __int_as_float(_ov), _oi); \
  } while (0)

__global__ __launch_bounds__(FPS_T) void fps_kernel(
    const float* __restrict__ xyz, float* __restrict__ centers,
    float* __restrict__ out_newxyz)
{
#pragma clang fp contract(off)
  __shared__ float sx[NN], sy[NN], sz[NN];
  __shared__ int sfar[NS];
  __shared__ float redv[2][FPS_T/64];
  __shared__ int   redi[2][FPS_T/64];
  const int b = blockIdx.x;
  const int tid = threadIdx.x;
  const float* xb = xyz + (size_t)b * NN * 3;
  for (int i = tid; i < NN; i += FPS_T) {
    sx[i] = xb[i*3+0]; sy[i] = xb[i*3+1]; sz[i] = xb[i*3+2];
  }
  __syncthreads();
  float px[PPT], py[PPT], pz[PPT], dist[PPT];
  const int base = tid * PPT;
#pragma unroll
  for (int j = 0; j < PPT; ++j) {
    px[j] = sx[base+j]; py[j] = sy[base+j]; pz[j] = sz[base+j];
    dist[j] = 1e10f;
  }
  float cx = sx[0], cy = sy[0], cz = sz[0];
  if (tid == 0) sfar[0] = 0;

  for (int it = 1; it < NS; ++it) {
    // distance update (parallel, no chain)
#pragma unroll
    for (int j = 0; j < PPT; ++j) {
      float dx = px[j]-cx, dy = py[j]-cy, dz = pz[j]-cz;
      float d = (dx*dx + dy*dy) + dz*dz;
      float dd = dist[j];
      dist[j] = d < dd ? d : dd;
    }
    // local argmax: tree over 16 (left operand always lower index -> strict >)
    float v8[8]; int i8[8];
#pragma unroll
    for (int j = 0; j < 8; ++j) {
      bool t = dist[2*j+1] > dist[2*j];
      v8[j] = t ? dist[2*j+1] : dist[2*j];
      i8[j] = base + (t ? 2*j+1 : 2*j);
    }
    float v4[4]; int i4[4];
#pragma unroll
    for (int j = 0; j < 4; ++j) {
      bool t = v8[2*j+1] > v8[2*j];
      v4[j] = t ? v8[2*j+1] : v8[2*j];
      i4[j] = t ? i8[2*j+1] : i8[2*j];
    }
    float v2[2]; int i2[2];
#pragma unroll
    for (int j = 0; j < 2; ++j) {
      bool t = v4[2*j+1] > v4[2*j];
      v2[j] = t ? v4[2*j+1] : v4[2*j];
      i2[j] = t ? i4[2*j+1] : i4[2*j];
    }
    bool t0 = v2[1] > v2[0];
    float bv = t0 ? v2[1] : v2[0];
    int   bi = t0 ? i2[1] : i2[0];
    // intra-row (16-lane) reduce via DPP row rotations: VALU speed
    DPP_AMAX_STEP(0x121);  // row_ror:1
    DPP_AMAX_STEP(0x122);  // row_ror:2
    DPP_AMAX_STEP(0x124);  // row_ror:4
    DPP_AMAX_STEP(0x128);  // row_ror:8
    // cross-row: xor16, xor32
    amax_merge(bv, bi, __shfl_xor(bv, 16), __shfl_xor(bi, 16));
    amax_merge(bv, bi, __shfl_xor(bv, 32), __shfl_xor(bi, 32));
    const int pb = it & 1;
    if ((tid & 63) == 0) { redv[pb][tid>>6] = bv; redi[pb][tid>>6] = bi; }
    __syncthreads();
    float fv = redv[pb][0]; int fi = redi[pb][0];
#pragma unroll
    for (int w = 1; w < FPS_T/64; ++w)
      amax_merge(fv, fi, redv[pb][w], redi[pb][w]);
    cx = sx[fi]; cy = sy[fi]; cz = sz[fi];
    if (tid == 0) sfar[it] = fi;
  }
  __syncthreads();
  for (int s = tid; s < NS; s += FPS_T) {
    int f = sfar[s];
    float x = sx[f], y = sy[f], z = sz[f];
    size_t o = ((size_t)b * NS + s) * 3;
    centers[o] = x; centers[o+1] = y; centers[o+2] = z;
    out_newxyz[o] = x; out_newxyz[o+1] = y; out_newxyz[o+2] = z;
  }
}

// ================================================================ ball query
__global__ __launch_bounds__(64) void ball_kernel(
    const float* __restrict__ xyz, const float* __restrict__ centers,
    int* __restrict__ group_idx)
{
#pragma clang fp contract(off)
  __shared__ float sx[NN], sy[NN], sz[NN];
  const int bid = blockIdx.x;       // 256 blocks: 16 per batch
  const int b = bid >> 4;
  const int s = ((bid & 15) << 6) + threadIdx.x;
  const float* xb = xyz + (size_t)b * NN * 3;
  for (int i = threadIdx.x; i < NN; i += 64) {
    sx[i] = xb[i*3+0]; sy[i] = xb[i*3+1]; sz[i] = xb[i*3+2];
  }
  __syncthreads();
  const size_t co = ((size_t)b * NS + s) * 3;
  const float cx = centers[co], cy = centers[co+1], cz = centers[co+2];
  const float csq = (cx*cx + cy*cy) + cz*cz;
  int* out = group_idx + ((size_t)b * NS + s) * NK;
  int count = 0, first = 0;
  for (int i = 0; i < NN; ++i) {
    const float x = sx[i], y = sy[i], z = sz[i];
    const float psq = (x*x + y*y) + z*z;
    const float dot = (cx*x + cy*y) + cz*z;
    const float dist = (csq + psq) - 2.0f*dot;
    if (dist <= 0.25f) {
      if (count == 0) first = i;
      if (count < NK) out[count] = i;
      count++;
    }
    if ((i & 63) == 63) {
      if (!__any(count < NK)) break;
    }
  }
  for (int r = count; r < NK; ++r) out[r] = first;
}

// ================================================================ prep
__global__ __launch_bounds__(256) void prep_kernel(
    const float* __restrict__ w0, const float* __restrict__ w1,
    const float* __restrict__ w2, float* __restrict__ wT)
{
  int i = blockIdx.x*256 + threadIdx.x;
  if (i < 4288) {
    int c = i >> 6, d = i & 63;
    wT[i] = w0[d*CIN0 + c];
  } else if (i < 8384) {
    int j = i - 4288; int c = j >> 6, d = j & 63;
    wT[i] = w1[d*64 + c];
  } else if (i < WT_TOTAL) {
    int j = i - 8384; int c = j >> 7, d = j & 127;
    wT[i] = w2[d*64 + c];
  }
}

// ================================================================ helpers
__device__ __forceinline__ float gelu_exact(float x) {
  return (0.5f * x) * (erff(x * 0.70710678118654752f) + 1.0f);
}
__device__ __forceinline__ float bf_lo(uint u) { return __uint_as_float(u << 16); }
__device__ __forceinline__ float bf_hi(uint u) { return __uint_as_float(u & 0xffff0000u); }
__device__ __forceinline__ uint bfpack(float a, float b) {
  uint ua = __float_as_uint(a), ub = __float_as_uint(b);
  // round-to-nearest-even on bit 16
  ua = (ua + 0x7fffu + ((ua >> 16) & 1u)) >> 16;
  ub = (ub + 0x7fffu + ((ub >> 16) & 1u)) >> 16;
  return (ua & 0xffffu) | (ub << 16);
}

__device__ __forceinline__ void fmac64(float (&acc)[64], const float* wrow, float xc) {
  const float4* wp = (const float4*)wrow;
#pragma unroll
  for (int i = 0; i < 16; ++i) {
    float4 w = wp[i];
    acc[i*4+0] = fmaf(xc, w.x, acc[i*4+0]);
    acc[i*4+1] = fmaf(xc, w.y, acc[i*4+1]);
    acc[i*4+2] = fmaf(xc, w.z, acc[i*4+2]);
    acc[i*4+3] = fmaf(xc, w.w, acc[i*4+3]);
  }
}
__device__ __forceinline__ void fmac128(float (&acc)[128], const float* wrow, float xc) {
  const float4* wp = (const float4*)wrow;
#pragma unroll
  for (int i = 0; i < 32; ++i) {
    float4 w = wp[i];
    acc[i*4+0] = fmaf(xc, w.x, acc[i*4+0]);
    acc[i*4+1] = fmaf(xc, w.y, acc[i*4+1]);
    acc[i*4+2] = fmaf(xc, w.z, acc[i*4+2]);
    acc[i*4+3] = fmaf(xc, w.w, acc[i*4+3]);
  }
}

// layer0 for point p into acc[64]; wsh = W0T [67][64] in LDS; b0v in LDS
__device__ __forceinline__ void layer0(
    const float* __restrict__ xyz, const float* __restrict__ feat,
    const float* __restrict__ centers, const int* __restrict__ gidx,
    const float* wsh, const float* b0v, int p, float (&acc)[64])
{
  const int b = p >> 15;
  const int s = (p & 32767) >> 5;
  const int gi = gidx[p];
#pragma unroll
  for (int d = 0; d < 64; ++d) acc[d] = b0v[d];
  const float* cp = centers + ((size_t)(b*NS + s))*3;
  const float* pp = xyz + ((size_t)(b*NN) + gi)*3;
  fmac64(acc, wsh + 0*64, pp[0]-cp[0]);
  fmac64(acc, wsh + 1*64, pp[1]-cp[1]);
  fmac64(acc, wsh + 2*64, pp[2]-cp[2]);
  const float4* fr = (const float4*)(feat + ((size_t)(b*NN) + gi)*64);
#pragma unroll 2
  for (int q = 0; q < 16; ++q) {
    float4 v = fr[q];
    fmac64(acc, wsh + (3+q*4)*64, v.x);
    fmac64(acc, wsh + (4+q*4)*64, v.y);
    fmac64(acc, wsh + (5+q*4)*64, v.z);
    fmac64(acc, wsh + (6+q*4)*64, v.w);
  }
}

// per-channel block column-sums of v into bsum/bssq
__device__ __forceinline__ void block_colsum64(const float (&v)[64], float* sbuf,
    float* bsum, float* bssq, int cbase)
{
  const int tid = threadIdx.x;
#pragma unroll
  for (int cc = 0; cc < 4; ++cc) {
    __syncthreads();
#pragma unroll
    for (int j = 0; j < 16; ++j) sbuf[tid*17 + j] = v[cc*16 + j];
    __syncthreads();
    const int c = tid & 15, seg = tid >> 4;
    float s = 0.f, q = 0.f;
#pragma unroll
    for (int i = 0; i < 16; ++i) {
      float x = sbuf[(seg*16 + i)*17 + c];
      s += x; q += x*x;
    }
    __syncthreads();
    sbuf[tid*2] = s; sbuf[tid*2+1] = q;
    __syncthreads();
    if (tid < 16) {
      float ss = 0.f, qq = 0.f;
#pragma unroll
      for (int sg = 0; sg < 16; ++sg) {
        ss += sbuf[(sg*16 + tid)*2];
        qq += sbuf[(sg*16 + tid)*2 + 1];
      }
      bsum[cbase + cc*16 + tid] += ss;
      bssq[cbase + cc*16 + tid] += qq;
    }
  }
  __syncthreads();
}

// ================================================================ tiered pipeline
// P0: gather + L0, write X (bf16 h0), stats0
__global__ __launch_bounds__(256,3) void p0_kernel(
    const float* __restrict__ xyz, const float* __restrict__ feat,
    const float* __restrict__ centers, const int* __restrict__ gidx,
    const float* __restrict__ wT, const float* __restrict__ b0,
    ushort* __restrict__ X, float* __restrict__ stat0)
{
  __shared__ float wsh[4288];
  __shared__ float sbuf[4352];
  __shared__ float bsum[64], bssq[64], b0s[64];
  const int tid = threadIdx.x;
  for (int i = tid; i < 1072; i += 256) ((float4*)wsh)[i] = ((const float4*)wT)[i];
  if (tid < 64) { bsum[tid] = 0.f; bssq[tid] = 0.f; b0s[tid] = b0[tid]; }
  __syncthreads();
  const int p = blockIdx.x*256 + tid;
  float acc[64];
  layer0(xyz, feat, centers, gidx, wsh, b0s, p, acc);
  // write X = bf16(h0)
  uint4* xr = (uint4*)(X + (size_t)p*64);
#pragma unroll
  for (int q = 0; q < 8; ++q) {
    uint4 pk;
    pk.x = bfpack(acc[q*8+0], acc[q*8+1]);
    pk.y = bfpack(acc[q*8+2], acc[q*8+3]);
    pk.z = bfpack(acc[q*8+4], acc[q*8+5]);
    pk.w = bfpack(acc[q*8+6], acc[q*8+7]);
    xr[q] = pk;
  }
  block_colsum64(acc, sbuf, bsum, bssq, 0);
  if (tid < 64) {
    atomicAdd(&stat0[tid], bsum[tid]);
    atomicAdd(&stat0[64+tid], bssq[tid]);
  }
}

// P1: read X (h0 bf16), bn0+gelu, L1, write X = bf16(h1), stats1
__global__ __launch_bounds__(256,3) void p1_kernel(
    ushort* X, const float* __restrict__ wT,
    const float* __restrict__ stat0, const float* __restrict__ g0,
    const float* __restrict__ be0, const float* __restrict__ b1,
    float* __restrict__ stat1)
{
  __shared__ float wsh[4096];   // W1T
  __shared__ float sbuf[4352];
  __shared__ float bsum[64], bssq[64];
  __shared__ float sc[64], sh[64], b1s[64];
  const int tid = threadIdx.x;
  for (int i = tid; i < 1024; i += 256)
    ((float4*)wsh)[i] = ((const float4*)(wT + W1T_OFF))[i];
  if (tid < 64) {
    float m0 = stat0[tid]*INV_NPTS;
    float v0 = stat0[64+tid]*INV_NPTS - m0*m0;
    float s0 = (1.0f/sqrtf(v0 + BN_EPS)) * g0[tid];
    sc[tid] = s0; sh[tid] = be0[tid] - m0*s0;
    b1s[tid] = b1[tid];
    bsum[tid] = 0.f; bssq[tid] = 0.f;
  }
  __syncthreads();
  const int p = blockIdx.x*256 + tid;
  uint4* xr = (uint4*)(X + (size_t)p*64);
  float acc[64];
#pragma unroll
  for (int d = 0; d < 64; ++d) acc[d] = b1s[d];
#pragma unroll 1
  for (int ch = 0; ch < 8; ++ch) {
    uint4 v = xr[ch];
    const int c = ch*8;
    float x0 = gelu_exact(fmaf(bf_lo(v.x), sc[c+0], sh[c+0]));
    float x1 = gelu_exact(fmaf(bf_hi(v.x), sc[c+1], sh[c+1]));
    float x2 = gelu_exact(fmaf(bf_lo(v.y), sc[c+2], sh[c+2]));
    float x3 = gelu_exact(fmaf(bf_hi(v.y), sc[c+3], sh[c+3]));
    float x4 = gelu_exact(fmaf(bf_lo(v.z), sc[c+4], sh[c+4]));
    float x5 = gelu_exact(fmaf(bf_hi(v.z), sc[c+5], sh[c+5]));
    float x6 = gelu_exact(fmaf(bf_lo(v.w), sc[c+6], sh[c+6]));
    float x7 = gelu_exact(fmaf(bf_hi(v.w), sc[c+7], sh[c+7]));
    fmac64(acc, wsh + (c+0)*64, x0);
    fmac64(acc, wsh + (c+1)*64, x1);
    fmac64(acc, wsh + (c+2)*64, x2);
    fmac64(acc, wsh + (c+3)*64, x3);
    fmac64(acc, wsh + (c+4)*64, x4);
    fmac64(acc, wsh + (c+5)*64, x5);
    fmac64(acc, wsh + (c+6)*64, x6);
    fmac64(acc, wsh + (c+7)*64, x7);
  }
#pragma unroll
  for (int q = 0; q < 8; ++q) {
    uint4 pk;
    pk.x = bfpack(acc[q*8+0], acc[q*8+1]);
    pk.y = bfpack(acc[q*8+2], acc[q*8+3]);
    pk.z = bfpack(acc[q*8+4], acc[q*8+5]);
    pk.w = bfpack(acc[q*8+6], acc[q*8+7]);
    xr[q] = pk;
  }
  block_colsum64(acc, sbuf, bsum, bssq, 0);
  if (tid < 64) {
    atomicAdd(&stat1[tid], bsum[tid]);
    atomicAdd(&stat1[64+tid], bssq[tid]);
  }
}

// P2: read X (h1 bf16), bn1+gelu -> x2, L2 -> acc[128], stats2.
// STORE_H2: write H2 = bf16(h2); else write X = bf16(x2) in place.
template<bool STORE_H2>
__global__ __launch_bounds__(256,2) void p2_kernel(
    ushort* X, ushort* __restrict__ H2, const float* __restrict__ wT,
    const float* __restrict__ stat1, const float* __restrict__ g1,
    const float* __restrict__ be1, const float* __restrict__ b2,
    float* __restrict__ stat2)
{
  __shared__ float wsh[8192];   // W2T [64][128]
  __shared__ float sbuf[4352];
  __shared__ float bsum[128], bssq[128];
  __shared__ float sc[64], sh[64], b2s[128];
  const int tid = threadIdx.x;
  for (int i = tid; i < 2048; i += 256)
    ((float4*)wsh)[i] = ((const float4*)(wT + W2T_OFF))[i];
  if (tid < 64) {
    float m1 = stat1[tid]*INV_NPTS;
    float v1 = stat1[64+tid]*INV_NPTS - m1*m1;
    float s1 = (1.0f/sqrtf(v1 + BN_EPS)) * g1[tid];
    sc[tid] = s1; sh[tid] = be1[tid] - m1*s1;
  }
  if (tid < 128) { b2s[tid] = b2[tid]; bsum[tid] = 0.f; bssq[tid] = 0.f; }
  __syncthreads();
  const int p = blockIdx.x*256 + tid;
  uint4* xr = (uint4*)(X + (size_t)p*64);
  float acc[128];
#pragma unroll
  for (int d = 0; d < 128; ++d) acc[d] = b2s[d];
#pragma unroll 1
  for (int ch = 0; ch < 8; ++ch) {
    uint4 v = xr[ch];
    const int c = ch*8;
    float x0 = gelu_exact(fmaf(bf_lo(v.x), sc[c+0], sh[c+0]));
    float x1 = gelu_exact(fmaf(bf_hi(v.x), sc[c+1], sh[c+1]));
    float x2 = gelu_exact(fmaf(bf_lo(v.y), sc[c+2], sh[c+2]));
    float x3 = gelu_exact(fmaf(bf_hi(v.y), sc[c+3], sh[c+3]));
    float x4 = gelu_exact(fmaf(bf_lo(v.z), sc[c+4], sh[c+4]));
    float x5 = gelu_exact(fmaf(bf_hi(v.z), sc[c+5], sh[c+5]));
    float x6 = gelu_exact(fmaf(bf_lo(v.w), sc[c+6], sh[c+6]));
    float x7 = gelu_exact(fmaf(bf_hi(v.w), sc[c+7], sh[c+7]));
    if (!STORE_H2) {
      uint4 pk;
      pk.x = bfpack(x0, x1); pk.y = bfpack(x2, x3);
      pk.z = bfpack(x4, x5); pk.w = bfpack(x6, x7);
      xr[ch] = pk;           // X row becomes x2 (same thread, read-then-write)
    }
    fmac128(acc, wsh + (c+0)*128, x0);
    fmac128(acc, wsh + (c+1)*128, x1);
    fmac128(acc, wsh + (c+2)*128, x2);
    fmac128(acc, wsh + (c+3)*128, x3);
    fmac128(acc, wsh + (c+4)*128, x4);
    fmac128(acc, wsh + (c+5)*128, x5);
    fmac128(acc, wsh + (c+6)*128, x6);
    fmac128(acc, wsh + (c+7)*128, x7);
  }
  if (STORE_H2) {
    uint4* hr = (uint4*)(H2 + (size_t)p*128);
#pragma unroll
    for (int q = 0; q < 16; ++q) {
      uint4 pk;
      pk.x = bfpack(acc[q*8+0], acc[q*8+1]);
      pk.y = bfpack(acc[q*8+2], acc[q*8+3]);
      pk.z = bfpack(acc[q*8+4], acc[q*8+5]);
      pk.w = bfpack(acc[q*8+6], acc[q*8+7]);
      hr[q] = pk;
    }
  }
#pragma unroll
  for (int half = 0; half < 2; ++half) {
    float tmp[64];
#pragma unroll
    for (int d = 0; d < 64; ++d) tmp[d] = acc[half*64 + d];
    block_colsum64(tmp, sbuf, bsum, bssq, half*64);
  }
  if (tid < 128) {
    atomicAdd(&stat2[tid], bsum[tid]);
    atomicAdd(&stat2[128+tid], bssq[tid]);
  }
}

// F big: stream H2, bn2+gelu+maxpool
__global__ __launch_bounds__(128) void fbig_kernel(
    const ushort* __restrict__ H2, const float* __restrict__ stat2,
    const float* __restrict__ g2, const float* __restrict__ be2,
    float* __restrict__ out_feat)
{
  const int d = threadIdx.x;
  const int bs = blockIdx.x;
  const float mean = stat2[d] * INV_NPTS;
  const float var  = stat2[128+d] * INV_NPTS - mean*mean;
  const float scale = (1.0f/sqrtf(var + BN_EPS)) * g2[d];
  const float shift = be2[d] - mean*scale;
  const ushort* rp = H2 + (size_t)bs*NK*128 + d;
  float m = -3.4e38f;
#pragma unroll 4
  for (int k = 0; k < NK; ++k) {
    float t = __uint_as_float(((uint)rp[k*128]) << 16);
    m = fmaxf(m, gelu_exact(fmaf(t, scale, shift)));
  }
  out_feat[(size_t)bs*128 + d] = m;
}

// F small: read X (x2 bf16), L2, bn2+gelu+maxpool over 32 lanes
__global__ __launch_bounds__(256,2) void fsmall_kernel(
    const ushort* __restrict__ X, const float* __restrict__ wT,
    const float* __restrict__ b2, const float* __restrict__ stat2,
    const float* __restrict__ g2, const float* __restrict__ be2,
    float* __restrict__ out_feat)
{
  __shared__ float wsh[8192];
  __shared__ float b2s[128], sc2[128], sh2[128];
  const int tid = threadIdx.x;
  for (int i = tid; i < 2048; i += 256)
    ((float4*)wsh)[i] = ((const float4*)(wT + W2T_OFF))[i];
  if (tid < 128) {
    b2s[tid] = b2[tid];
    float m2 = stat2[tid]*INV_NPTS;
    float v2 = stat2[128+tid]*INV_NPTS - m2*m2;
    float s2 = (1.0f/sqrtf(v2 + BN_EPS)) * g2[tid];
    sc2[tid] = s2; sh2[tid] = be2[tid] - m2*s2;
  }
  __syncthreads();
  const int p = blockIdx.x*256 + tid;
  const int bs = p >> 5;
  const uint4* xr = (const uint4*)(X + (size_t)p*64);
  float acc[128];
#pragma unroll
  for (int d = 0; d < 128; ++d) acc[d] = b2s[d];
#pragma unroll 1
  for (int ch = 0; ch < 8; ++ch) {
    uint4 v = xr[ch];
    const int c = ch*8;
    fmac128(acc, wsh + (c+0)*128, bf_lo(v.x));
    fmac128(acc, wsh + (c+1)*128, bf_hi(v.x));
    fmac128(acc, wsh + (c+2)*128, bf_lo(v.y));
    fmac128(acc, wsh + (c+3)*128, bf_hi(v.y));
    fmac128(acc, wsh + (c+4)*128, bf_lo(v.z));
    fmac128(acc, wsh + (c+5)*128, bf_hi(v.z));
    fmac128(acc, wsh + (c+6)*128, bf_lo(v.w));
    fmac128(acc, wsh + (c+7)*128, bf_hi(v.w));
  }
#pragma unroll
  for (int d = 0; d < 128; ++d) {
    float y = gelu_exact(fmaf(acc[d], sc2[d], sh2[d]));
#pragma unroll
    for (int m = 1; m < 32; m <<= 1) y = fmaxf(y, __shfl_xor(y, m));
    acc[d] = y;
  }
  if ((tid & 31) == 0) {
    float4* op = (float4*)(out_feat + (size_t)bs*128);
#pragma unroll
    for (int i = 0; i < 32; ++i)
      op[i] = make_float4(acc[i*4], acc[i*4+1], acc[i*4+2], acc[i*4+3]);
  }
}

// ================================================================ fallback (validated round-2 recompute path)
__device__ __forceinline__ void chain_to_x2(
    const float* __restrict__ xyz, const float* __restrict__ feat,
    const float* __restrict__ centers, const int* __restrict__ gidx,
    const float* wsh, float* sbuf, const float* prm, int p, float (&x2)[64])
{
  float acc0[64];
  layer0(xyz, feat, centers, gidx, wsh, prm, p, acc0);
#pragma unroll
  for (int c = 0; c < 64; ++c) acc0[c] = gelu_exact(fmaf(acc0[c], prm[64+c], prm[128+c]));
#pragma unroll
  for (int d = 0; d < 64; ++d) x2[d] = prm[192+d];
  float* xrow = sbuf + threadIdx.x*17;
#pragma unroll
  for (int cc = 0; cc < 4; ++cc) {
#pragma unroll
    for (int j = 0; j < 16; ++j) xrow[j] = acc0[cc*16 + j];
#pragma unroll 1
    for (int cj = 0; cj < 16; ++cj)
      fmac64(x2, wsh + W1T_OFF + (cc*16+cj)*64, xrow[cj]);
  }
#pragma unroll
  for (int c = 0; c < 64; ++c) x2[c] = gelu_exact(fmaf(x2[c], prm[256+c], prm[320+c]));
}

__global__ __launch_bounds__(256,2) void s0_kernel(
    const float* __restrict__ xyz, const float* __restrict__ feat,
    const float* __restrict__ centers, const int* __restrict__ gidx,
    const float* __restrict__ wT, const float* __restrict__ b0,
    float* __restrict__ stat0)
{
  __shared__ float wsh[4288];
  __shared__ float sbuf[4352];
  __shared__ float bsum[64], bssq[64], b0s[64];
  const int tid = threadIdx.x;
  for (int i = tid; i < 1072; i += 256) ((float4*)wsh)[i] = ((const float4*)wT)[i];
  if (tid < 64) { bsum[tid] = 0.f; bssq[tid] = 0.f; b0s[tid] = b0[tid]; }
  __syncthreads();
  const int p = blockIdx.x*256 + tid;
  float acc[64];
  layer0(xyz, feat, centers, gidx, wsh, b0s, p, acc);
  block_colsum64(acc, sbuf, bsum, bssq, 0);
  if (tid < 64) {
    atomicAdd(&stat0[tid], bsum[tid]);
    atomicAdd(&stat0[64+tid], bssq[tid]);
  }
}

__global__ __launch_bounds__(256,2) void s1_kernel(
    const float* __restrict__ xyz, const float* __restrict__ feat,
    const float* __restrict__ centers, const int* __restrict__ gidx,
    const float* __restrict__ wT, const float* __restrict__ stat0,
    const float* __restrict__ g0, const float* __restrict__ be0,
    const float* __restrict__ b0, const float* __restrict__ b1,
    float* __restrict__ stat1)
{
  __shared__ float wsh[8384];
  __shared__ float sbuf[4352];
  __shared__ float bsum[64], bssq[64];
  __shared__ float prm[256];
  const int tid = threadIdx.x;
  for (int i = tid; i < 2096; i += 256) ((float4*)wsh)[i] = ((const float4*)wT)[i];
  if (tid < 64) {
    float m0 = stat0[tid]*INV_NPTS;
    float v0 = stat0[64+tid]*INV_NPTS - m0*m0;
    float sc0 = (1.0f/sqrtf(v0 + BN_EPS)) * g0[tid];
    prm[tid] = b0[tid]; prm[64+tid] = sc0; prm[128+tid] = be0[tid] - m0*sc0;
    prm[192+tid] = b1[tid];
    bsum[tid] = 0.f; bssq[tid] = 0.f;
  }
  __syncthreads();
  const int p = blockIdx.x*256 + tid;
  float acc0[64];
  layer0(xyz, feat, centers, gidx, wsh, prm, p, acc0);
#pragma unroll
  for (int c = 0; c < 64; ++c) acc0[c] = gelu_exact(fmaf(acc0[c], prm[64+c], prm[128+c]));
  float acc1[64];
#pragma unroll
  for (int d = 0; d < 64; ++d) acc1[d] = prm[192+d];
  float* xrow = sbuf + tid*17;
#pragma unroll
  for (int cc = 0; cc < 4; ++cc) {
#pragma unroll
    for (int j = 0; j < 16; ++j) xrow[j] = acc0[cc*16 + j];
#pragma unroll 1
    for (int cj = 0; cj < 16; ++cj)
      fmac64(acc1, wsh + W1T_OFF + (cc*16+cj)*64, xrow[cj]);
  }
  block_colsum64(acc1, sbuf, bsum, bssq, 0);
  if (tid < 64) {
    atomicAdd(&stat1[tid], bsum[tid]);
    atomicAdd(&stat1[64+tid], bssq[tid]);
  }
}

__global__ __launch_bounds__(256,2) void s2_kernel(
    const float* __restrict__ xyz, const float* __restrict__ feat,
    const float* __restrict__ centers, const int* __restrict__ gidx,
    const float* __restrict__ wT,
    const float* __restrict__ stat0, const float* __restrict__ g0,
    const float* __restrict__ be0, const float* __restrict__ b0,
    const float* __restrict__ b1, const float* __restrict__ stat1,
    const float* __restrict__ g1, const float* __restrict__ be1,
    const float* __restrict__ b2, float* __restrict__ stat2)
{
  __shared__ float wsh[8384];
  __shared__ float sbuf[4352];
  __shared__ float bsum[128], bssq[128];
  __shared__ float prm[512];
  const int tid = threadIdx.x;
  for (int i = tid; i < 2096; i += 256) ((float4*)wsh)[i] = ((const float4*)wT)[i];
  if (tid < 64) {
    float m0 = stat0[tid]*INV_NPTS;
    float v0 = stat0[64+tid]*INV_NPTS - m0*m0;
    float sc0 = (1.0f/sqrtf(v0 + BN_EPS)) * g0[tid];
    prm[tid] = b0[tid]; prm[64+tid] = sc0; prm[128+tid] = be0[tid] - m0*sc0;
    float m1 = stat1[tid]*INV_NPTS;
    float v1 = stat1[64+tid]*INV_NPTS - m1*m1;
    float sc1 = (1.0f/sqrtf(v1 + BN_EPS)) * g1[tid];
    prm[192+tid] = b1[tid]; prm[256+tid] = sc1; prm[320+tid] = be1[tid] - m1*sc1;
  }
  if (tid < 128) { prm[384+tid] = b2[tid]; bsum[tid] = 0.f; bssq[tid] = 0.f; }
  __syncthreads();
  const int p = blockIdx.x*256 + tid;
  float x2[64];
  chain_to_x2(xyz, feat, centers, gidx, wsh, sbuf, prm, p, x2);
  __syncthreads();
  for (int i = tid; i < 2048; i += 256)
    ((float4*)wsh)[i] = ((const float4*)(wT + W2T_OFF))[i];
  __syncthreads();
  float* xrow = sbuf + tid*17;
#pragma unroll 1
  for (int half = 0; half < 2; ++half) {
    float a2[64];
#pragma unroll
    for (int d = 0; d < 64; ++d) a2[d] = prm[384 + half*64 + d];
#pragma unroll
    for (int cc = 0; cc < 4; ++cc) {
#pragma unroll
      for (int j = 0; j < 16; ++j) xrow[j] = x2[cc*16 + j];
#pragma unroll 1
      for (int cj = 0; cj < 16; ++cj)
        fmac64(a2, wsh + (cc*16+cj)*128 + half*64, xrow[cj]);
    }
    block_colsum64(a2, sbuf, bsum, bssq, half*64);
  }
  if (tid < 128) {
    atomicAdd(&stat2[tid], bsum[tid]);
    atomicAdd(&stat2[128+tid], bssq[tid]);
  }
}

__global__ __launch_bounds__(256,2) void fin_kernel(
    const float* __restrict__ xyz, const float* __restrict__ feat,
    const float* __restrict__ centers, const int* __restrict__ gidx,
    const float* __restrict__ wT,
    const float* __restrict__ stat0, const float* __restrict__ g0,
    const float* __restrict__ be0, const float* __restrict__ b0,
    const float* __restrict__ b1, const float* __restrict__ stat1,
    const float* __restrict__ g1, const float* __restrict__ be1,
    const float* __restrict__ b2, const float* __restrict__ stat2,
    const float* __restrict__ g2, const float* __restrict__ be2,
    float* __restrict__ out_feat)
{
  __shared__ float wsh[8384];
  __shared__ float sbuf[4352];
  __shared__ float prm[768];
  const int tid = threadIdx.x;
  for (int i = tid; i < 2096; i += 256) ((float4*)wsh)[i] = ((const float4*)wT)[i];
  if (tid < 64) {
    float m0 = stat0[tid]*INV_NPTS;
    float v0 = stat0[64+tid]*INV_NPTS - m0*m0;
    float sc0 = (1.0f/sqrtf(v0 + BN_EPS)) * g0[tid];
    prm[tid] = b0[tid]; prm[64+tid] = sc0; prm[128+tid] = be0[tid] - m0*sc0;
    float m1 = stat1[tid]*INV_NPTS;
    float v1 = stat1[64+tid]*INV_NPTS - m1*m1;
    float sc1 = (1.0f/sqrtf(v1 + BN_EPS)) * g1[tid];
    prm[192+tid] = b1[tid]; prm[256+tid] = sc1; prm[320+tid] = be1[tid] - m1*sc1;
  }
  if (tid < 128) {
    prm[384+tid] = b2[tid];
    float m2 = stat2[tid]*INV_NPTS;
    float v2 = stat2[128+tid]*INV_NPTS - m2*m2;
    float sc2 = (1.0f/sqrtf(v2 + BN_EPS)) * g2[tid];
    prm[512+tid] = sc2; prm[640+tid] = be2[tid] - m2*sc2;
  }
  __syncthreads();
  const int p = blockIdx.x*256 + tid;
  const int b = p >> 15;
  const int s = (p & 32767) >> 5;
  float x2[64];
  chain_to_x2(xyz, feat, centers, gidx, wsh, sbuf, prm, p, x2);
  __syncthreads();
  for (int i = tid; i < 2048; i += 256)
    ((float4*)wsh)[i] = ((const float4*)(wT + W2T_OFF))[i];
  __syncthreads();
  float* xrow = sbuf + tid*17;
#pragma unroll 1
  for (int half = 0; half < 2; ++half) {
    float a2[64];
#pragma unroll
    for (int d = 0; d < 64; ++d) a2[d] = prm[384 + half*64 + d];
#pragma unroll
    for (int cc = 0; cc < 4; ++cc) {
#pragma unroll
      for (int j = 0; j < 16; ++j) xrow[j] = x2[cc*16 + j];
#pragma unroll 1
      for (int cj = 0; cj < 16; ++cj)
        fmac64(a2, wsh + (cc*16+cj)*128 + half*64, xrow[cj]);
    }
#pragma unroll
    for (int d = 0; d < 64; ++d) {
      float y = gelu_exact(fmaf(a2[d], prm[512 + half*64 + d], prm[640 + half*64 + d]));
#pragma unroll
      for (int m = 1; m < 32; m <<= 1) y = fmaxf(y, __shfl_xor(y, m));
      a2[d] = y;
    }
    if ((tid & 31) == 0) {
      float4* op = (float4*)(out_feat + ((size_t)(b*NS + s))*128 + half*64);
#pragma unroll
      for (int i = 0; i < 16; ++i)
        op[i] = make_float4(a2[i*4], a2[i*4+1], a2[i*4+2], a2[i*4+3]);
    }
  }
}

// ================================================================ launch
extern "C" void kernel_launch(void* const* d_in, const int* in_sizes, int n_in,
                              void* d_out, int out_size, void* d_ws, size_t ws_size,
                              hipStream_t stream) {
  (void)in_sizes; (void)n_in; (void)out_size;
  const float* xyz      = (const float*)d_in[0];
  const float* features = (const float*)d_in[1];
  const float* w0  = (const float*)d_in[2];
  const float* b0  = (const float*)d_in[3];
  const float* g0  = (const float*)d_in[4];
  const float* be0 = (const float*)d_in[5];
  const float* w1  = (const float*)d_in[6];
  const float* b1  = (const float*)d_in[7];
  const float* g1  = (const float*)d_in[8];
  const float* be1 = (const float*)d_in[9];
  const float* w2  = (const float*)d_in[10];
  const float* b2  = (const float*)d_in[11];
  const float* g2  = (const float*)d_in[12];
  const float* be2 = (const float*)d_in[13];

  float* out = (float*)d_out;
  float* out_newxyz = out;                 // (16,1024,3)
  float* out_feat   = out + NB*NS*3;       // (16,1024,128)

  char* ws = (char*)d_ws;
  size_t off = 0;
  float* centers   = (float*)(ws + off); off += (size_t)NB*NS*3*4;
  int*   group_idx = (int*)(ws + off);   off += (size_t)NPTS*4;
  float* stats     = (float*)(ws + off); off += 512*4;
  off = (off + 255) & ~(size_t)255;
  float* wT        = (float*)(ws + off); off += (size_t)WT_TOTAL*4;
  off = (off + 255) & ~(size_t)255;
  const size_t base_end = off;
  const size_t X_bytes  = (size_t)NPTS*64*2;   // 67.1 MB
  const size_t H2_bytes = (size_t)NPTS*128*2;  // 134.2 MB
  ushort* X  = (ushort*)(ws + base_end);
  ushort* H2 = (ushort*)(ws + base_end + X_bytes);

  const bool tier_big   = ws_size >= base_end + X_bytes + H2_bytes;
  const bool tier_small = !tier_big && ws_size >= base_end + X_bytes;
  if (ws_size < base_end) return;

  float* stat0 = stats;
  float* stat1 = stats + 128;
  float* stat2 = stats + 256;

  (void)hipMemsetAsync(stats, 0, 2048, stream);
  prep_kernel<<<65, 256, 0, stream>>>(w0, w1, w2, wT);
  fps_kernel<<<NB, FPS_T, 0, stream>>>(xyz, centers, out_newxyz);
  ball_kernel<<<256, 64, 0, stream>>>(xyz, centers, group_idx);

  if (tier_big || tier_small) {
    p0_kernel<<<NPTS/256, 256, 0, stream>>>(xyz, features, centers, group_idx,
                                            wT, b0, X, stat0);
    p1_kernel<<<NPTS/256, 256, 0, stream>>>(X, wT, stat0, g0, be0, b1, stat1);
    if (tier_big) {
      p2_kernel<true><<<NPTS/256, 256, 0, stream>>>(X, H2, wT, stat1, g1, be1, b2, stat2);
      fbig_kernel<<<NB*NS, 128, 0, stream>>>(H2, stat2, g2, be2, out_feat);
    } else {
      p2_kernel<false><<<NPTS/256, 256, 0, stream>>>(X, H2, wT, stat1, g1, be1, b2, stat2);
      fsmall_kernel<<<NPTS/256, 256, 0, stream>>>(X, wT, b2, stat2, g2, be2, out_feat);
    }
  } else {
    s0_kernel<<<NPTS/256, 256, 0, stream>>>(xyz, features, centers, group_idx, wT, b0, stat0);
    s1_kernel<<<NPTS/256, 256, 0, stream>>>(xyz, features, centers, group_idx, wT,
                                            stat0, g0, be0, b0, b1, stat1);
    s2_kernel<<<NPTS/256, 256, 0, stream>>>(xyz, features, centers, group_idx, wT,
                                            stat0, g0, be0, b0, b1, stat1, g1, be1, b2, stat2);
    fin_kernel<<<NPTS/256, 256, 0, stream>>>(xyz, features, centers, group_idx, wT,
                                             stat0, g0, be0, b0, b1, stat1, g1, be1, b2,
                                             stat2, g2, be2, out_feat);
  }
}

// Round 5
// 2213.719 us; speedup vs baseline: 1.5179x; 1.0514x over previous
//
#include <hip/hip_runtime.h>

typedef unsigned int uint;
typedef unsigned short ushort;

#define NB 16
#define NN 4096
#define NS 1024
#define NK 32
#define CIN0 67
#define NPTS (NB*NS*NK)           // 524288
#define BN_EPS 1e-5f
#define INV_NPTS (1.0f/524288.0f) // exact power of two

// transposed-weight offsets inside wT (floats)
#define W0T_OFF 0      // [67][64]  = 4288
#define W1T_OFF 4288   // [64][64]  = 4096
#define W2T_OFF 8384   // [64][128] = 8192
#define WT_TOTAL 16576

// ================================================================ FPS v3
// 256 threads (4 waves), 16 pts/thread. DPP row_ror reduce intra-row, DPP
// row_bcast15/31 cross-row (result valid in lane 63 of each wave), packed
// (v,i) cross-wave merge via 2 uniform ds_read_b128. Points in float4 LDS so
// centroid fetch is a single b128. Argmax: max value, min index on tie.
#define FPS_T 256
#define PPT (NN / FPS_T) // 16

__device__ __forceinline__ void amax_merge(float& bv, int& bi, float ov, int oi) {
  if (ov > bv || (ov == bv && oi < bi)) { bv = ov; bi = oi; }
}

// dpp_ctrl: row_ror:N = 0x120+N ; row_bcast15 = 0x142 ; row_bcast31 = 0x143
#define DPP_AMAX_STEP(CTRL) do { \
    int _ov = __builtin_amdgcn_update_dpp(0, __float_as_int(bv), (CTRL), 0xF, 0xF, true); \
    int _oi = __builtin_amdgcn_update_dpp(0, bi,                 (CTRL), 0xF, 0xF, true); \
    amax_merge(bv, bi, __int_as_float(_ov), _oi); \
  } while (0)

__global__ __launch_bounds__(FPS_T) void fps_kernel(
    const float* __restrict__ xyz, float* __restrict__ centers,
    float* __restrict__ out_newxyz)
{
#pragma clang fp contract(off)
  __shared__ float4 sxyz[NN];                    // 64 KB
  __shared__ int sfar[NS];
  __shared__ __align__(16) uint2 sred[2][FPS_T/64];
  const int b = blockIdx.x;
  const int tid = threadIdx.x;
  const float* xb = xyz + (size_t)b * NN * 3;
  for (int i = tid; i < NN; i += FPS_T)
    sxyz[i] = make_float4(xb[i*3+0], xb[i*3+1], xb[i*3+2], 0.f);
  __syncthreads();
  float px[PPT], py[PPT], pz[PPT], dist[PPT];
  const int base = tid * PPT;
#pragma unroll
  for (int j = 0; j < PPT; ++j) {
    float4 P = sxyz[base+j];
    px[j] = P.x; py[j] = P.y; pz[j] = P.z;
    dist[j] = 1e10f;
  }
  float4 C0 = sxyz[0];
  float cx = C0.x, cy = C0.y, cz = C0.z;
  if (tid == 0) sfar[0] = 0;

  for (int it = 1; it < NS; ++it) {
    // distance update (independent per point)
#pragma unroll
    for (int j = 0; j < PPT; ++j) {
      float dx = px[j]-cx, dy = py[j]-cy, dz = pz[j]-cz;
      float d = (dx*dx + dy*dy) + dz*dz;
      float dd = dist[j];
      dist[j] = d < dd ? d : dd;
    }
    // local argmax tree (left operand lower index -> strict >)
    float v8[8]; int i8[8];
#pragma unroll
    for (int j = 0; j < 8; ++j) {
      bool t = dist[2*j+1] > dist[2*j];
      v8[j] = t ? dist[2*j+1] : dist[2*j];
      i8[j] = base + (t ? 2*j+1 : 2*j);
    }
    float v4[4]; int i4[4];
#pragma unroll
    for (int j = 0; j < 4; ++j) {
      bool t = v8[2*j+1] > v8[2*j];
      v4[j] = t ? v8[2*j+1] : v8[2*j];
      i4[j] = t ? i8[2*j+1] : i8[2*j];
    }
    float v2[2]; int i2[2];
#pragma unroll
    for (int j = 0; j < 2; ++j) {
      bool t = v4[2*j+1] > v4[2*j];
      v2[j] = t ? v4[2*j+1] : v4[2*j];
      i2[j] = t ? i4[2*j+1] : i4[2*j];
    }
    bool t0 = v2[1] > v2[0];
    float bv = t0 ? v2[1] : v2[0];
    int   bi = t0 ? i2[1] : i2[0];
    // intra-row (16) rotation reduce: every lane gets its row's argmax
    DPP_AMAX_STEP(0x121);
    DPP_AMAX_STEP(0x122);
    DPP_AMAX_STEP(0x124);
    DPP_AMAX_STEP(0x128);
    // cross-row: bcast15 (row0->1, row2->3), bcast31 (rows01 -> 32..63).
    // Full-wave result valid in lanes 48..63; lane 63 writes.
    DPP_AMAX_STEP(0x142);
    DPP_AMAX_STEP(0x143);
    const int pb = it & 1;
    if ((tid & 63) == 63) sred[pb][tid>>6] = make_uint2(__float_as_uint(bv), (uint)bi);
    __syncthreads();
    uint4 ra = *((const uint4*)&sred[pb][0]);
    uint4 rb = *((const uint4*)&sred[pb][2]);
    float fv = __uint_as_float(ra.x); int fi = (int)ra.y;
    amax_merge(fv, fi, __uint_as_float(ra.z), (int)ra.w);
    amax_merge(fv, fi, __uint_as_float(rb.x), (int)rb.y);
    amax_merge(fv, fi, __uint_as_float(rb.z), (int)rb.w);
    float4 C = sxyz[fi];
    cx = C.x; cy = C.y; cz = C.z;
    if (tid == 0) sfar[it] = fi;
  }
  __syncthreads();
  for (int s = tid; s < NS; s += FPS_T) {
    int f = sfar[s];
    float4 C = sxyz[f];
    size_t o = ((size_t)b * NS + s) * 3;
    centers[o] = C.x; centers[o+1] = C.y; centers[o+2] = C.z;
    out_newxyz[o] = C.x; out_newxyz[o+1] = C.y; out_newxyz[o+2] = C.z;
  }
}

// ================================================================ ball query
__global__ __launch_bounds__(64) void ball_kernel(
    const float* __restrict__ xyz, const float* __restrict__ centers,
    int* __restrict__ group_idx)
{
#pragma clang fp contract(off)
  __shared__ float sx[NN], sy[NN], sz[NN];
  const int bid = blockIdx.x;       // 256 blocks: 16 per batch
  const int b = bid >> 4;
  const int s = ((bid & 15) << 6) + threadIdx.x;
  const float* xb = xyz + (size_t)b * NN * 3;
  for (int i = threadIdx.x; i < NN; i += 64) {
    sx[i] = xb[i*3+0]; sy[i] = xb[i*3+1]; sz[i] = xb[i*3+2];
  }
  __syncthreads();
  const size_t co = ((size_t)b * NS + s) * 3;
  const float cx = centers[co], cy = centers[co+1], cz = centers[co+2];
  const float csq = (cx*cx + cy*cy) + cz*cz;
  int* out = group_idx + ((size_t)b * NS + s) * NK;
  int count = 0, first = 0;
  for (int i = 0; i < NN; ++i) {
    const float x = sx[i], y = sy[i], z = sz[i];
    const float psq = (x*x + y*y) + z*z;
    const float dot = (cx*x + cy*y) + cz*z;
    const float dist = (csq + psq) - 2.0f*dot;
    if (dist <= 0.25f) {
      if (count == 0) first = i;
      if (count < NK) out[count] = i;
      count++;
    }
    if ((i & 63) == 63) {
      if (!__any(count < NK)) break;
    }
  }
  for (int r = count; r < NK; ++r) out[r] = first;
}

// ================================================================ prep
__global__ __launch_bounds__(256) void prep_kernel(
    const float* __restrict__ w0, const float* __restrict__ w1,
    const float* __restrict__ w2, float* __restrict__ wT)
{
  int i = blockIdx.x*256 + threadIdx.x;
  if (i < 4288) {
    int c = i >> 6, d = i & 63;
    wT[i] = w0[d*CIN0 + c];
  } else if (i < 8384) {
    int j = i - 4288; int c = j >> 6, d = j & 63;
    wT[i] = w1[d*64 + c];
  } else if (i < WT_TOTAL) {
    int j = i - 8384; int c = j >> 7, d = j & 127;
    wT[i] = w2[d*64 + c];
  }
}

// ================================================================ helpers
// Branchless gelu: erf via Abramowitz-Stegun 7.1.26 (|err|<~2e-6 incl. rcp/exp
// approx). Output shift vs exact erf <= ~1e-5 -- negligible vs 0.15 threshold.
__device__ __forceinline__ float gelu_f(float x) {
  float z = fabsf(x) * 0.70710678118654752f;
  float t = __builtin_amdgcn_rcpf(fmaf(0.3275911f, z, 1.0f));
  float p = t * fmaf(t, fmaf(t, fmaf(t, fmaf(t, 1.061405429f, -1.453152027f),
                                     1.421413741f), -0.284496736f), 0.254829592f);
  float ex = __expf(-z*z);
  float er = fmaf(-p, ex, 1.0f);   // erf(|x|/sqrt2) >= 0
  float se = __uint_as_float(__float_as_uint(er) | (__float_as_uint(x) & 0x80000000u));
  return 0.5f * x * (1.0f + se);
}
__device__ __forceinline__ float bf_lo(uint u) { return __uint_as_float(u << 16); }
__device__ __forceinline__ float bf_hi(uint u) { return __uint_as_float(u & 0xffff0000u); }
__device__ __forceinline__ uint bfpack(float a, float b) {
  uint ua = __float_as_uint(a), ub = __float_as_uint(b);
  ua = (ua + 0x7fffu + ((ua >> 16) & 1u)) >> 16;   // RNE on bit 16
  ub = (ub + 0x7fffu + ((ub >> 16) & 1u)) >> 16;
  return (ua & 0xffffu) | (ub << 16);
}

__device__ __forceinline__ void fmac64(float (&acc)[64], const float* wrow, float xc) {
  const float4* wp = (const float4*)wrow;
#pragma unroll
  for (int i = 0; i < 16; ++i) {
    float4 w = wp[i];
    acc[i*4+0] = fmaf(xc, w.x, acc[i*4+0]);
    acc[i*4+1] = fmaf(xc, w.y, acc[i*4+1]);
    acc[i*4+2] = fmaf(xc, w.z, acc[i*4+2]);
    acc[i*4+3] = fmaf(xc, w.w, acc[i*4+3]);
  }
}
__device__ __forceinline__ void fmac128(float (&acc)[128], const float* wrow, float xc) {
  const float4* wp = (const float4*)wrow;
#pragma unroll
  for (int i = 0; i < 32; ++i) {
    float4 w = wp[i];
    acc[i*4+0] = fmaf(xc, w.x, acc[i*4+0]);
    acc[i*4+1] = fmaf(xc, w.y, acc[i*4+1]);
    acc[i*4+2] = fmaf(xc, w.z, acc[i*4+2]);
    acc[i*4+3] = fmaf(xc, w.w, acc[i*4+3]);
  }
}

// layer0 for point p into acc[64]; wsh = W0T [67][64] in LDS; b0v in LDS.
// Feature reads software-pipelined 1-deep (compute >> load latency).
__device__ __forceinline__ void layer0(
    const float* __restrict__ xyz, const float* __restrict__ feat,
    const float* __restrict__ centers, const int* __restrict__ gidx,
    const float* wsh, const float* b0v, int p, float (&acc)[64])
{
  const int b = p >> 15;
  const int s = (p & 32767) >> 5;
  const int gi = gidx[p];
#pragma unroll
  for (int d = 0; d < 64; ++d) acc[d] = b0v[d];
  const float* cp = centers + ((size_t)(b*NS + s))*3;
  const float* pp = xyz + ((size_t)(b*NN) + gi)*3;
  const float4* fr = (const float4*)(feat + ((size_t)(b*NN) + gi)*64);
  float4 f = fr[0];
  fmac64(acc, wsh + 0*64, pp[0]-cp[0]);
  fmac64(acc, wsh + 1*64, pp[1]-cp[1]);
  fmac64(acc, wsh + 2*64, pp[2]-cp[2]);
#pragma unroll 1
  for (int q = 0; q < 16; ++q) {
    const int nq = (q < 15) ? q + 1 : 15;
    float4 fn = fr[nq];
    fmac64(acc, wsh + (3+q*4)*64, f.x);
    fmac64(acc, wsh + (4+q*4)*64, f.y);
    fmac64(acc, wsh + (5+q*4)*64, f.z);
    fmac64(acc, wsh + (6+q*4)*64, f.w);
    f = fn;
  }
}

// per-channel block column-sums of v into bsum/bssq
__device__ __forceinline__ void block_colsum64(const float (&v)[64], float* sbuf,
    float* bsum, float* bssq, int cbase)
{
  const int tid = threadIdx.x;
#pragma unroll
  for (int cc = 0; cc < 4; ++cc) {
    __syncthreads();
#pragma unroll
    for (int j = 0; j < 16; ++j) sbuf[tid*17 + j] = v[cc*16 + j];
    __syncthreads();
    const int c = tid & 15, seg = tid >> 4;
    float s = 0.f, q = 0.f;
#pragma unroll
    for (int i = 0; i < 16; ++i) {
      float x = sbuf[(seg*16 + i)*17 + c];
      s += x; q += x*x;
    }
    __syncthreads();
    sbuf[tid*2] = s; sbuf[tid*2+1] = q;
    __syncthreads();
    if (tid < 16) {
      float ss = 0.f, qq = 0.f;
#pragma unroll
      for (int sg = 0; sg < 16; ++sg) {
        ss += sbuf[(sg*16 + tid)*2];
        qq += sbuf[(sg*16 + tid)*2 + 1];
      }
      bsum[cbase + cc*16 + tid] += ss;
      bssq[cbase + cc*16 + tid] += qq;
    }
  }
  __syncthreads();
}

// ================================================================ tiered pipeline
// P0: gather + L0, write X (bf16 h0), stats0
__global__ __launch_bounds__(256,3) void p0_kernel(
    const float* __restrict__ xyz, const float* __restrict__ feat,
    const float* __restrict__ centers, const int* __restrict__ gidx,
    const float* __restrict__ wT, const float* __restrict__ b0,
    ushort* __restrict__ X, float* __restrict__ stat0)
{
  __shared__ float wsh[4288];
  __shared__ float sbuf[4352];
  __shared__ float bsum[64], bssq[64], b0s[64];
  const int tid = threadIdx.x;
  for (int i = tid; i < 1072; i += 256) ((float4*)wsh)[i] = ((const float4*)wT)[i];
  if (tid < 64) { bsum[tid] = 0.f; bssq[tid] = 0.f; b0s[tid] = b0[tid]; }
  __syncthreads();
  const int p = blockIdx.x*256 + tid;
  float acc[64];
  layer0(xyz, feat, centers, gidx, wsh, b0s, p, acc);
  uint4* xr = (uint4*)(X + (size_t)p*64);
#pragma unroll
  for (int q = 0; q < 8; ++q) {
    uint4 pk;
    pk.x = bfpack(acc[q*8+0], acc[q*8+1]);
    pk.y = bfpack(acc[q*8+2], acc[q*8+3]);
    pk.z = bfpack(acc[q*8+4], acc[q*8+5]);
    pk.w = bfpack(acc[q*8+6], acc[q*8+7]);
    xr[q] = pk;
  }
  block_colsum64(acc, sbuf, bsum, bssq, 0);
  if (tid < 64) {
    atomicAdd(&stat0[tid], bsum[tid]);
    atomicAdd(&stat0[64+tid], bssq[tid]);
  }
}

// P1: read X (h0 bf16), bn0+gelu, L1, write X = bf16(h1), stats1
__global__ __launch_bounds__(256,3) void p1_kernel(
    ushort* X, const float* __restrict__ wT,
    const float* __restrict__ stat0, const float* __restrict__ g0,
    const float* __restrict__ be0, const float* __restrict__ b1,
    float* __restrict__ stat1)
{
  __shared__ float wsh[4096];   // W1T
  __shared__ float sbuf[4352];
  __shared__ float bsum[64], bssq[64];
  __shared__ float sc[64], sh[64], b1s[64];
  const int tid = threadIdx.x;
  for (int i = tid; i < 1024; i += 256)
    ((float4*)wsh)[i] = ((const float4*)(wT + W1T_OFF))[i];
  if (tid < 64) {
    float m0 = stat0[tid]*INV_NPTS;
    float v0 = stat0[64+tid]*INV_NPTS - m0*m0;
    float s0 = (1.0f/sqrtf(v0 + BN_EPS)) * g0[tid];
    sc[tid] = s0; sh[tid] = be0[tid] - m0*s0;
    b1s[tid] = b1[tid];
    bsum[tid] = 0.f; bssq[tid] = 0.f;
  }
  __syncthreads();
  const int p = blockIdx.x*256 + tid;
  uint4* xr = (uint4*)(X + (size_t)p*64);
  float acc[64];
#pragma unroll
  for (int d = 0; d < 64; ++d) acc[d] = b1s[d];
  uint4 v = xr[0];
#pragma unroll 1
  for (int ch = 0; ch < 8; ++ch) {
    const int nc = (ch < 7) ? ch + 1 : 7;
    uint4 vn = xr[nc];
    const int c = ch*8;
    float x0 = gelu_f(fmaf(bf_lo(v.x), sc[c+0], sh[c+0]));
    float x1 = gelu_f(fmaf(bf_hi(v.x), sc[c+1], sh[c+1]));
    float x2 = gelu_f(fmaf(bf_lo(v.y), sc[c+2], sh[c+2]));
    float x3 = gelu_f(fmaf(bf_hi(v.y), sc[c+3], sh[c+3]));
    float x4 = gelu_f(fmaf(bf_lo(v.z), sc[c+4], sh[c+4]));
    float x5 = gelu_f(fmaf(bf_hi(v.z), sc[c+5], sh[c+5]));
    float x6 = gelu_f(fmaf(bf_lo(v.w), sc[c+6], sh[c+6]));
    float x7 = gelu_f(fmaf(bf_hi(v.w), sc[c+7], sh[c+7]));
    fmac64(acc, wsh + (c+0)*64, x0);
    fmac64(acc, wsh + (c+1)*64, x1);
    fmac64(acc, wsh + (c+2)*64, x2);
    fmac64(acc, wsh + (c+3)*64, x3);
    fmac64(acc, wsh + (c+4)*64, x4);
    fmac64(acc, wsh + (c+5)*64, x5);
    fmac64(acc, wsh + (c+6)*64, x6);
    fmac64(acc, wsh + (c+7)*64, x7);
    v = vn;
  }
#pragma unroll
  for (int q = 0; q < 8; ++q) {
    uint4 pk;
    pk.x = bfpack(acc[q*8+0], acc[q*8+1]);
    pk.y = bfpack(acc[q*8+2], acc[q*8+3]);
    pk.z = bfpack(acc[q*8+4], acc[q*8+5]);
    pk.w = bfpack(acc[q*8+6], acc[q*8+7]);
    xr[q] = pk;
  }
  block_colsum64(acc, sbuf, bsum, bssq, 0);
  if (tid < 64) {
    atomicAdd(&stat1[tid], bsum[tid]);
    atomicAdd(&stat1[64+tid], bssq[tid]);
  }
}

// P2: read X (h1 bf16), bn1+gelu -> x2, L2 -> acc[128], stats2.
template<bool STORE_H2>
__global__ __launch_bounds__(256,2) void p2_kernel(
    ushort* X, ushort* __restrict__ H2, const float* __restrict__ wT,
    const float* __restrict__ stat1, const float* __restrict__ g1,
    const float* __restrict__ be1, const float* __restrict__ b2,
    float* __restrict__ stat2)
{
  __shared__ float wsh[8192];   // W2T [64][128]
  __shared__ float sbuf[4352];
  __shared__ float bsum[128], bssq[128];
  __shared__ float sc[64], sh[64], b2s[128];
  const int tid = threadIdx.x;
  for (int i = tid; i < 2048; i += 256)
    ((float4*)wsh)[i] = ((const float4*)(wT + W2T_OFF))[i];
  if (tid < 64) {
    float m1 = stat1[tid]*INV_NPTS;
    float v1 = stat1[64+tid]*INV_NPTS - m1*m1;
    float s1 = (1.0f/sqrtf(v1 + BN_EPS)) * g1[tid];
    sc[tid] = s1; sh[tid] = be1[tid] - m1*s1;
  }
  if (tid < 128) { b2s[tid] = b2[tid]; bsum[tid] = 0.f; bssq[tid] = 0.f; }
  __syncthreads();
  const int p = blockIdx.x*256 + tid;
  uint4* xr = (uint4*)(X + (size_t)p*64);
  float acc[128];
#pragma unroll
  for (int d = 0; d < 128; ++d) acc[d] = b2s[d];
  uint4 v = xr[0];
#pragma unroll 1
  for (int ch = 0; ch < 8; ++ch) {
    const int nc = (ch < 7) ? ch + 1 : 7;
    uint4 vn = xr[nc];
    const int c = ch*8;
    float x0 = gelu_f(fmaf(bf_lo(v.x), sc[c+0], sh[c+0]));
    float x1 = gelu_f(fmaf(bf_hi(v.x), sc[c+1], sh[c+1]));
    float x2 = gelu_f(fmaf(bf_lo(v.y), sc[c+2], sh[c+2]));
    float x3 = gelu_f(fmaf(bf_hi(v.y), sc[c+3], sh[c+3]));
    float x4 = gelu_f(fmaf(bf_lo(v.z), sc[c+4], sh[c+4]));
    float x5 = gelu_f(fmaf(bf_hi(v.z), sc[c+5], sh[c+5]));
    float x6 = gelu_f(fmaf(bf_lo(v.w), sc[c+6], sh[c+6]));
    float x7 = gelu_f(fmaf(bf_hi(v.w), sc[c+7], sh[c+7]));
    if (!STORE_H2) {
      uint4 pk;
      pk.x = bfpack(x0, x1); pk.y = bfpack(x2, x3);
      pk.z = bfpack(x4, x5); pk.w = bfpack(x6, x7);
      xr[ch] = pk;
    }
    fmac128(acc, wsh + (c+0)*128, x0);
    fmac128(acc, wsh + (c+1)*128, x1);
    fmac128(acc, wsh + (c+2)*128, x2);
    fmac128(acc, wsh + (c+3)*128, x3);
    fmac128(acc, wsh + (c+4)*128, x4);
    fmac128(acc, wsh + (c+5)*128, x5);
    fmac128(acc, wsh + (c+6)*128, x6);
    fmac128(acc, wsh + (c+7)*128, x7);
    v = vn;
  }
  if (STORE_H2) {
    uint4* hr = (uint4*)(H2 + (size_t)p*128);
#pragma unroll
    for (int q = 0; q < 16; ++q) {
      uint4 pk;
      pk.x = bfpack(acc[q*8+0], acc[q*8+1]);
      pk.y = bfpack(acc[q*8+2], acc[q*8+3]);
      pk.z = bfpack(acc[q*8+4], acc[q*8+5]);
      pk.w = bfpack(acc[q*8+6], acc[q*8+7]);
      hr[q] = pk;
    }
  }
#pragma unroll
  for (int half = 0; half < 2; ++half) {
    float tmp[64];
#pragma unroll
    for (int d = 0; d < 64; ++d) tmp[d] = acc[half*64 + d];
    block_colsum64(tmp, sbuf, bsum, bssq, half*64);
  }
  if (tid < 128) {
    atomicAdd(&stat2[tid], bsum[tid]);
    atomicAdd(&stat2[128+tid], bssq[tid]);
  }
}

// F big: stream H2, bn2+gelu+maxpool (TLP hides latency: 16384 blocks)
__global__ __launch_bounds__(128) void fbig_kernel(
    const ushort* __restrict__ H2, const float* __restrict__ stat2,
    const float* __restrict__ g2, const float* __restrict__ be2,
    float* __restrict__ out_feat)
{
  const int d = threadIdx.x;
  const int bs = blockIdx.x;
  const float mean = stat2[d] * INV_NPTS;
  const float var  = stat2[128+d] * INV_NPTS - mean*mean;
  const float scale = (1.0f/sqrtf(var + BN_EPS)) * g2[d];
  const float shift = be2[d] - mean*scale;
  const ushort* rp = H2 + (size_t)bs*NK*128 + d;
  float m = -3.4e38f;
#pragma unroll 4
  for (int k = 0; k < NK; ++k) {
    float t = __uint_as_float(((uint)rp[k*128]) << 16);
    m = fmaxf(m, gelu_f(fmaf(t, scale, shift)));
  }
  out_feat[(size_t)bs*128 + d] = m;
}

// F small: read X (x2 bf16), L2, bn2+gelu+maxpool over 32 lanes
__global__ __launch_bounds__(256,2) void fsmall_kernel(
    const ushort* __restrict__ X, const float* __restrict__ wT,
    const float* __restrict__ b2, const float* __restrict__ stat2,
    const float* __restrict__ g2, const float* __restrict__ be2,
    float* __restrict__ out_feat)
{
  __shared__ float wsh[8192];
  __shared__ float b2s[128], sc2[128], sh2[128];
  const int tid = threadIdx.x;
  for (int i = tid; i < 2048; i += 256)
    ((float4*)wsh)[i] = ((const float4*)(wT + W2T_OFF))[i];
  if (tid < 128) {
    b2s[tid] = b2[tid];
    float m2 = stat2[tid]*INV_NPTS;
    float v2 = stat2[128+tid]*INV_NPTS - m2*m2;
    float s2 = (1.0f/sqrtf(v2 + BN_EPS)) * g2[tid];
    sc2[tid] = s2; sh2[tid] = be2[tid] - m2*s2;
  }
  __syncthreads();
  const int p = blockIdx.x*256 + tid;
  const int bs = p >> 5;
  const uint4* xr = (const uint4*)(X + (size_t)p*64);
  float acc[128];
#pragma unroll
  for (int d = 0; d < 128; ++d) acc[d] = b2s[d];
  uint4 v = xr[0];
#pragma unroll 1
  for (int ch = 0; ch < 8; ++ch) {
    const int nc = (ch < 7) ? ch + 1 : 7;
    uint4 vn = xr[nc];
    const int c = ch*8;
    fmac128(acc, wsh + (c+0)*128, bf_lo(v.x));
    fmac128(acc, wsh + (c+1)*128, bf_hi(v.x));
    fmac128(acc, wsh + (c+2)*128, bf_lo(v.y));
    fmac128(acc, wsh + (c+3)*128, bf_hi(v.y));
    fmac128(acc, wsh + (c+4)*128, bf_lo(v.z));
    fmac128(acc, wsh + (c+5)*128, bf_hi(v.z));
    fmac128(acc, wsh + (c+6)*128, bf_lo(v.w));
    fmac128(acc, wsh + (c+7)*128, bf_hi(v.w));
    v = vn;
  }
#pragma unroll
  for (int d = 0; d < 128; ++d) {
    float y = gelu_f(fmaf(acc[d], sc2[d], sh2[d]));
#pragma unroll
    for (int m = 1; m < 32; m <<= 1) y = fmaxf(y, __shfl_xor(y, m));
    acc[d] = y;
  }
  if ((tid & 31) == 0) {
    float4* op = (float4*)(out_feat + (size_t)bs*128);
#pragma unroll
    for (int i = 0; i < 32; ++i)
      op[i] = make_float4(acc[i*4], acc[i*4+1], acc[i*4+2], acc[i*4+3]);
  }
}

// ================================================================ fallback (recompute path)
__device__ __forceinline__ void chain_to_x2(
    const float* __restrict__ xyz, const float* __restrict__ feat,
    const float* __restrict__ centers, const int* __restrict__ gidx,
    const float* wsh, float* sbuf, const float* prm, int p, float (&x2)[64])
{
  float acc0[64];
  layer0(xyz, feat, centers, gidx, wsh, prm, p, acc0);
#pragma unroll
  for (int c = 0; c < 64; ++c) acc0[c] = gelu_f(fmaf(acc0[c], prm[64+c], prm[128+c]));
#pragma unroll
  for (int d = 0; d < 64; ++d) x2[d] = prm[192+d];
  float* xrow = sbuf + threadIdx.x*17;
#pragma unroll
  for (int cc = 0; cc < 4; ++cc) {
#pragma unroll
    for (int j = 0; j < 16; ++j) xrow[j] = acc0[cc*16 + j];
#pragma unroll 1
    for (int cj = 0; cj < 16; ++cj)
      fmac64(x2, wsh + W1T_OFF + (cc*16+cj)*64, xrow[cj]);
  }
#pragma unroll
  for (int c = 0; c < 64; ++c) x2[c] = gelu_f(fmaf(x2[c], prm[256+c], prm[320+c]));
}

__global__ __launch_bounds__(256,2) void s0_kernel(
    const float* __restrict__ xyz, const float* __restrict__ feat,
    const float* __restrict__ centers, const int* __restrict__ gidx,
    const float* __restrict__ wT, const float* __restrict__ b0,
    float* __restrict__ stat0)
{
  __shared__ float wsh[4288];
  __shared__ float sbuf[4352];
  __shared__ float bsum[64], bssq[64], b0s[64];
  const int tid = threadIdx.x;
  for (int i = tid; i < 1072; i += 256) ((float4*)wsh)[i] = ((const float4*)wT)[i];
  if (tid < 64) { bsum[tid] = 0.f; bssq[tid] = 0.f; b0s[tid] = b0[tid]; }
  __syncthreads();
  const int p = blockIdx.x*256 + tid;
  float acc[64];
  layer0(xyz, feat, centers, gidx, wsh, b0s, p, acc);
  block_colsum64(acc, sbuf, bsum, bssq, 0);
  if (tid < 64) {
    atomicAdd(&stat0[tid], bsum[tid]);
    atomicAdd(&stat0[64+tid], bssq[tid]);
  }
}

__global__ __launch_bounds__(256,2) void s1_kernel(
    const float* __restrict__ xyz, const float* __restrict__ feat,
    const float* __restrict__ centers, const int* __restrict__ gidx,
    const float* __restrict__ wT, const float* __restrict__ stat0,
    const float* __restrict__ g0, const float* __restrict__ be0,
    const float* __restrict__ b0, const float* __restrict__ b1,
    float* __restrict__ stat1)
{
  __shared__ float wsh[8384];
  __shared__ float sbuf[4352];
  __shared__ float bsum[64], bssq[64];
  __shared__ float prm[256];
  const int tid = threadIdx.x;
  for (int i = tid; i < 2096; i += 256) ((float4*)wsh)[i] = ((const float4*)wT)[i];
  if (tid < 64) {
    float m0 = stat0[tid]*INV_NPTS;
    float v0 = stat0[64+tid]*INV_NPTS - m0*m0;
    float sc0 = (1.0f/sqrtf(v0 + BN_EPS)) * g0[tid];
    prm[tid] = b0[tid]; prm[64+tid] = sc0; prm[128+tid] = be0[tid] - m0*sc0;
    prm[192+tid] = b1[tid];
    bsum[tid] = 0.f; bssq[tid] = 0.f;
  }
  __syncthreads();
  const int p = blockIdx.x*256 + tid;
  float acc0[64];
  layer0(xyz, feat, centers, gidx, wsh, prm, p, acc0);
#pragma unroll
  for (int c = 0; c < 64; ++c) acc0[c] = gelu_f(fmaf(acc0[c], prm[64+c], prm[128+c]));
  float acc1[64];
#pragma unroll
  for (int d = 0; d < 64; ++d) acc1[d] = prm[192+d];
  float* xrow = sbuf + tid*17;
#pragma unroll
  for (int cc = 0; cc < 4; ++cc) {
#pragma unroll
    for (int j = 0; j < 16; ++j) xrow[j] = acc0[cc*16 + j];
#pragma unroll 1
    for (int cj = 0; cj < 16; ++cj)
      fmac64(acc1, wsh + W1T_OFF + (cc*16+cj)*64, xrow[cj]);
  }
  block_colsum64(acc1, sbuf, bsum, bssq, 0);
  if (tid < 64) {
    atomicAdd(&stat1[tid], bsum[tid]);
    atomicAdd(&stat1[64+tid], bssq[tid]);
  }
}

__global__ __launch_bounds__(256,2) void s2_kernel(
    const float* __restrict__ xyz, const float* __restrict__ feat,
    const float* __restrict__ centers, const int* __restrict__ gidx,
    const float* __restrict__ wT,
    const float* __restrict__ stat0, const float* __restrict__ g0,
    const float* __restrict__ be0, const float* __restrict__ b0,
    const float* __restrict__ b1, const float* __restrict__ stat1,
    const float* __restrict__ g1, const float* __restrict__ be1,
    const float* __restrict__ b2, float* __restrict__ stat2)
{
  __shared__ float wsh[8384];
  __shared__ float sbuf[4352];
  __shared__ float bsum[128], bssq[128];
  __shared__ float prm[512];
  const int tid = threadIdx.x;
  for (int i = tid; i < 2096; i += 256) ((float4*)wsh)[i] = ((const float4*)wT)[i];
  if (tid < 64) {
    float m0 = stat0[tid]*INV_NPTS;
    float v0 = stat0[64+tid]*INV_NPTS - m0*m0;
    float sc0 = (1.0f/sqrtf(v0 + BN_EPS)) * g0[tid];
    prm[tid] = b0[tid]; prm[64+tid] = sc0; prm[128+tid] = be0[tid] - m0*sc0;
    float m1 = stat1[tid]*INV_NPTS;
    float v1 = stat1[64+tid]*INV_NPTS - m1*m1;
    float sc1 = (1.0f/sqrtf(v1 + BN_EPS)) * g1[tid];
    prm[192+tid] = b1[tid]; prm[256+tid] = sc1; prm[320+tid] = be1[tid] - m1*sc1;
  }
  if (tid < 128) { prm[384+tid] = b2[tid]; bsum[tid] = 0.f; bssq[tid] = 0.f; }
  __syncthreads();
  const int p = blockIdx.x*256 + tid;
  float x2[64];
  chain_to_x2(xyz, feat, centers, gidx, wsh, sbuf, prm, p, x2);
  __syncthreads();
  for (int i = tid; i < 2048; i += 256)
    ((float4*)wsh)[i] = ((const float4*)(wT + W2T_OFF))[i];
  __syncthreads();
  float* xrow = sbuf + tid*17;
#pragma unroll 1
  for (int half = 0; half < 2; ++half) {
    float a2[64];
#pragma unroll
    for (int d = 0; d < 64; ++d) a2[d] = prm[384 + half*64 + d];
#pragma unroll
    for (int cc = 0; cc < 4; ++cc) {
#pragma unroll
      for (int j = 0; j < 16; ++j) xrow[j] = x2[cc*16 + j];
#pragma unroll 1
      for (int cj = 0; cj < 16; ++cj)
        fmac64(a2, wsh + (cc*16+cj)*128 + half*64, xrow[cj]);
    }
    block_colsum64(a2, sbuf, bsum, bssq, half*64);
  }
  if (tid < 128) {
    atomicAdd(&stat2[tid], bsum[tid]);
    atomicAdd(&stat2[128+tid], bssq[tid]);
  }
}

__global__ __launch_bounds__(256,2) void fin_kernel(
    const float* __restrict__ xyz, const float* __restrict__ feat,
    const float* __restrict__ centers, const int* __restrict__ gidx,
    const float* __restrict__ wT,
    const float* __restrict__ stat0, const float* __restrict__ g0,
    const float* __restrict__ be0, const float* __restrict__ b0,
    const float* __restrict__ b1, const float* __restrict__ stat1,
    const float* __restrict__ g1, const float* __restrict__ be1,
    const float* __restrict__ b2, const float* __restrict__ stat2,
    const float* __restrict__ g2, const float* __restrict__ be2,
    float* __restrict__ out_feat)
{
  __shared__ float wsh[8384];
  __shared__ float sbuf[4352];
  __shared__ float prm[768];
  const int tid = threadIdx.x;
  for (int i = tid; i < 2096; i += 256) ((float4*)wsh)[i] = ((const float4*)wT)[i];
  if (tid < 64) {
    float m0 = stat0[tid]*INV_NPTS;
    float v0 = stat0[64+tid]*INV_NPTS - m0*m0;
    float sc0 = (1.0f/sqrtf(v0 + BN_EPS)) * g0[tid];
    prm[tid] = b0[tid]; prm[64+tid] = sc0; prm[128+tid] = be0[tid] - m0*sc0;
    float m1 = stat1[tid]*INV_NPTS;
    float v1 = stat1[64+tid]*INV_NPTS - m1*m1;
    float sc1 = (1.0f/sqrtf(v1 + BN_EPS)) * g1[tid];
    prm[192+tid] = b1[tid]; prm[256+tid] = sc1; prm[320+tid] = be1[tid] - m1*sc1;
  }
  if (tid < 128) {
    prm[384+tid] = b2[tid];
    float m2 = stat2[tid]*INV_NPTS;
    float v2 = stat2[128+tid]*INV_NPTS - m2*m2;
    float sc2 = (1.0f/sqrtf(v2 + BN_EPS)) * g2[tid];
    prm[512+tid] = sc2; prm[640+tid] = be2[tid] - m2*sc2;
  }
  __syncthreads();
  const int p = blockIdx.x*256 + tid;
  const int b = p >> 15;
  const int s = (p & 32767) >> 5;
  float x2[64];
  chain_to_x2(xyz, feat, centers, gidx, wsh, sbuf, prm, p, x2);
  __syncthreads();
  for (int i = tid; i < 2048; i += 256)
    ((float4*)wsh)[i] = ((const float4*)(wT + W2T_OFF))[i];
  __syncthreads();
  float* xrow = sbuf + tid*17;
#pragma unroll 1
  for (int half = 0; half < 2; ++half) {
    float a2[64];
#pragma unroll
    for (int d = 0; d < 64; ++d) a2[d] = prm[384 + half*64 + d];
#pragma unroll
    for (int cc = 0; cc < 4; ++cc) {
#pragma unroll
      for (int j = 0; j < 16; ++j) xrow[j] = x2[cc*16 + j];
#pragma unroll 1
      for (int cj = 0; cj < 16; ++cj)
        fmac64(a2, wsh + (cc*16+cj)*128 + half*64, xrow[cj]);
    }
#pragma unroll
    for (int d = 0; d < 64; ++d) {
      float y = gelu_f(fmaf(a2[d], prm[512 + half*64 + d], prm[640 + half*64 + d]));
#pragma unroll
      for (int m = 1; m < 32; m <<= 1) y = fmaxf(y, __shfl_xor(y, m));
      a2[d] = y;
    }
    if ((tid & 31) == 0) {
      float4* op = (float4*)(out_feat + ((size_t)(b*NS + s))*128 + half*64);
#pragma unroll
      for (int i = 0; i < 16; ++i)
        op[i] = make_float4(a2[i*4], a2[i*4+1], a2[i*4+2], a2[i*4+3]);
    }
  }
}

// ================================================================ launch
extern "C" void kernel_launch(void* const* d_in, const int* in_sizes, int n_in,
                              void* d_out, int out_size, void* d_ws, size_t ws_size,
                              hipStream_t stream) {
  (void)in_sizes; (void)n_in; (void)out_size;
  const float* xyz      = (const float*)d_in[0];
  const float* features = (const float*)d_in[1];
  const float* w0  = (const float*)d_in[2];
  const float* b0  = (const float*)d_in[3];
  const float* g0  = (const float*)d_in[4];
  const float* be0 = (const float*)d_in[5];
  const float* w1  = (const float*)d_in[6];
  const float* b1  = (const float*)d_in[7];
  const float* g1  = (const float*)d_in[8];
  const float* be1 = (const float*)d_in[9];
  const float* w2  = (const float*)d_in[10];
  const float* b2  = (const float*)d_in[11];
  const float* g2  = (const float*)d_in[12];
  const float* be2 = (const float*)d_in[13];

  float* out = (float*)d_out;
  float* out_newxyz = out;                 // (16,1024,3)
  float* out_feat   = out + NB*NS*3;       // (16,1024,128)

  char* ws = (char*)d_ws;
  size_t off = 0;
  float* centers   = (float*)(ws + off); off += (size_t)NB*NS*3*4;
  int*   group_idx = (int*)(ws + off);   off += (size_t)NPTS*4;
  float* stats     = (float*)(ws + off); off += 512*4;
  off = (off + 255) & ~(size_t)255;
  float* wT        = (float*)(ws + off); off += (size_t)WT_TOTAL*4;
  off = (off + 255) & ~(size_t)255;
  const size_t base_end = off;
  const size_t X_bytes  = (size_t)NPTS*64*2;   // 67.1 MB
  const size_t H2_bytes = (size_t)NPTS*128*2;  // 134.2 MB
  ushort* X  = (ushort*)(ws + base_end);
  ushort* H2 = (ushort*)(ws + base_end + X_bytes);

  const bool tier_big   = ws_size >= base_end + X_bytes + H2_bytes;
  const bool tier_small = !tier_big && ws_size >= base_end + X_bytes;
  if (ws_size < base_end) return;

  float* stat0 = stats;
  float* stat1 = stats + 128;
  float* stat2 = stats + 256;

  (void)hipMemsetAsync(stats, 0, 2048, stream);
  prep_kernel<<<65, 256, 0, stream>>>(w0, w1, w2, wT);
  fps_kernel<<<NB, FPS_T, 0, stream>>>(xyz, centers, out_newxyz);
  ball_kernel<<<256, 64, 0, stream>>>(xyz, centers, group_idx);

  if (tier_big || tier_small) {
    p0_kernel<<<NPTS/256, 256, 0, stream>>>(xyz, features, centers, group_idx,
                                            wT, b0, X, stat0);
    p1_kernel<<<NPTS/256, 256, 0, stream>>>(X, wT, stat0, g0, be0, b1, stat1);
    if (tier_big) {
      p2_kernel<true><<<NPTS/256, 256, 0, stream>>>(X, H2, wT, stat1, g1, be1, b2, stat2);
      fbig_kernel<<<NB*NS, 128, 0, stream>>>(H2, stat2, g2, be2, out_feat);
    } else {
      p2_kernel<false><<<NPTS/256, 256, 0, stream>>>(X, H2, wT, stat1, g1, be1, b2, stat2);
      fsmall_kernel<<<NPTS/256, 256, 0, stream>>>(X, wT, b2, stat2, g2, be2, out_feat);
    }
  } else {
    s0_kernel<<<NPTS/256, 256, 0, stream>>>(xyz, features, centers, group_idx, wT, b0, stat0);
    s1_kernel<<<NPTS/256, 256, 0, stream>>>(xyz, features, centers, group_idx, wT,
                                            stat0, g0, be0, b0, b1, stat1);
    s2_kernel<<<NPTS/256, 256, 0, stream>>>(xyz, features, centers, group_idx, wT,
                                            stat0, g0, be0, b0, b1, stat1, g1, be1, b2, stat2);
    fin_kernel<<<NPTS/256, 256, 0, stream>>>(xyz, features, centers, group_idx, wT,
                                             stat0, g0, be0, b0, b1, stat1, g1, be1, b2,
                                             stat2, g2, be2, out_feat);
  }
}

// Round 6
// 1642.471 us; speedup vs baseline: 2.0458x; 1.3478x over previous
//
#include <hip/hip_runtime.h>

typedef unsigned int uint;
typedef unsigned short ushort;

#define NB 16
#define NN 4096
#define NS 1024
#define NK 32
#define CIN0 67
#define NPTS (NB*NS*NK)           // 524288
#define BN_EPS 1e-5f
#define INV_NPTS (1.0f/524288.0f) // exact power of two

// transposed-weight offsets inside wT (floats)
#define W0T_OFF 0      // [67][64]  = 4288
#define W1T_OFF 4288   // [64][64]  = 4096
#define W2T_OFF 8384   // [64][128] = 8192
#define WT_TOTAL 16576

// ================================================================ FPS v3
#define FPS_T 256
#define PPT (NN / FPS_T) // 16

__device__ __forceinline__ void amax_merge(float& bv, int& bi, float ov, int oi) {
  if (ov > bv || (ov == bv && oi < bi)) { bv = ov; bi = oi; }
}

// dpp_ctrl: row_ror:N = 0x120+N ; row_bcast15 = 0x142 ; row_bcast31 = 0x143
#define DPP_AMAX_STEP(CTRL) do { \
    int _ov = __builtin_amdgcn_update_dpp(0, __float_as_int(bv), (CTRL), 0xF, 0xF, true); \
    int _oi = __builtin_amdgcn_update_dpp(0, bi,                 (CTRL), 0xF, 0xF, true); \
    amax_merge(bv, bi, __int_as_float(_ov), _oi); \
  } while (0)

__global__ __launch_bounds__(FPS_T) void fps_kernel(
    const float* __restrict__ xyz, float* __restrict__ centers,
    float* __restrict__ out_newxyz)
{
#pragma clang fp contract(off)
  __shared__ float4 sxyz[NN];                    // 64 KB
  __shared__ int sfar[NS];
  __shared__ __align__(16) uint2 sred[2][FPS_T/64];
  const int b = blockIdx.x;
  const int tid = threadIdx.x;
  const float* xb = xyz + (size_t)b * NN * 3;
  for (int i = tid; i < NN; i += FPS_T)
    sxyz[i] = make_float4(xb[i*3+0], xb[i*3+1], xb[i*3+2], 0.f);
  __syncthreads();
  float px[PPT], py[PPT], pz[PPT], dist[PPT];
  const int base = tid * PPT;
#pragma unroll
  for (int j = 0; j < PPT; ++j) {
    float4 P = sxyz[base+j];
    px[j] = P.x; py[j] = P.y; pz[j] = P.z;
    dist[j] = 1e10f;
  }
  float4 C0 = sxyz[0];
  float cx = C0.x, cy = C0.y, cz = C0.z;
  if (tid == 0) sfar[0] = 0;

  for (int it = 1; it < NS; ++it) {
#pragma unroll
    for (int j = 0; j < PPT; ++j) {
      float dx = px[j]-cx, dy = py[j]-cy, dz = pz[j]-cz;
      float d = (dx*dx + dy*dy) + dz*dz;
      float dd = dist[j];
      dist[j] = d < dd ? d : dd;
    }
    float v8[8]; int i8[8];
#pragma unroll
    for (int j = 0; j < 8; ++j) {
      bool t = dist[2*j+1] > dist[2*j];
      v8[j] = t ? dist[2*j+1] : dist[2*j];
      i8[j] = base + (t ? 2*j+1 : 2*j);
    }
    float v4[4]; int i4[4];
#pragma unroll
    for (int j = 0; j < 4; ++j) {
      bool t = v8[2*j+1] > v8[2*j];
      v4[j] = t ? v8[2*j+1] : v8[2*j];
      i4[j] = t ? i8[2*j+1] : i8[2*j];
    }
    float v2[2]; int i2[2];
#pragma unroll
    for (int j = 0; j < 2; ++j) {
      bool t = v4[2*j+1] > v4[2*j];
      v2[j] = t ? v4[2*j+1] : v4[2*j];
      i2[j] = t ? i4[2*j+1] : i4[2*j];
    }
    bool t0 = v2[1] > v2[0];
    float bv = t0 ? v2[1] : v2[0];
    int   bi = t0 ? i2[1] : i2[0];
    DPP_AMAX_STEP(0x121);
    DPP_AMAX_STEP(0x122);
    DPP_AMAX_STEP(0x124);
    DPP_AMAX_STEP(0x128);
    DPP_AMAX_STEP(0x142);
    DPP_AMAX_STEP(0x143);
    const int pb = it & 1;
    if ((tid & 63) == 63) sred[pb][tid>>6] = make_uint2(__float_as_uint(bv), (uint)bi);
    __syncthreads();
    uint4 ra = *((const uint4*)&sred[pb][0]);
    uint4 rb = *((const uint4*)&sred[pb][2]);
    float fv = __uint_as_float(ra.x); int fi = (int)ra.y;
    amax_merge(fv, fi, __uint_as_float(ra.z), (int)ra.w);
    amax_merge(fv, fi, __uint_as_float(rb.x), (int)rb.y);
    amax_merge(fv, fi, __uint_as_float(rb.z), (int)rb.w);
    float4 C = sxyz[fi];
    cx = C.x; cy = C.y; cz = C.z;
    if (tid == 0) sfar[it] = fi;
  }
  __syncthreads();
  for (int s = tid; s < NS; s += FPS_T) {
    int f = sfar[s];
    float4 C = sxyz[f];
    size_t o = ((size_t)b * NS + s) * 3;
    centers[o] = C.x; centers[o+1] = C.y; centers[o+2] = C.z;
    out_newxyz[o] = C.x; out_newxyz[o+1] = C.y; out_newxyz[o+2] = C.z;
  }
}

// ================================================================ ball query v2
// Wave-parallel: one wave per center (4 centers/wave sequentially). Lane L owns
// contiguous chunk [64L, 64L+64) -> 64-bit match mask; lane prefix-sum; lanes
// with base<32 emit matches (chunk order => global ascending = reference's
// sort-take-32). Pad with first match (>=1 always: center is its own point,
// dist == 0 exactly). LDS padded +1 float per 64 (addr = i + (i>>6)): contiguous
// chunks would put all 64 lanes on bank j%32 (64-way conflict); pad gives bank
// (L+j)%32 -> 2-way aliasing (free, m136).
#define BPAD(i) ((i) + ((i)>>6))
__global__ __launch_bounds__(256,2) void ball_kernel(
    const float* __restrict__ xyz, const float* __restrict__ centers,
    int* __restrict__ group_idx)
{
#pragma clang fp contract(off)
  __shared__ float sx[4160], sy[4160], sz[4160], sq[4160];  // 65 KB
  const int bid = blockIdx.x;            // 1024 blocks: 64 per batch
  const int b = bid >> 6;
  const int c0 = (bid & 63) << 4;        // 16 centers per block
  const int tid = threadIdx.x;
  const int lane = tid & 63;
  const int wave = tid >> 6;
  const float* xb = xyz + (size_t)b * NN * 3;
  for (int i = tid; i < NN; i += 256) {
    float x = xb[i*3+0], y = xb[i*3+1], z = xb[i*3+2];
    int a = BPAD(i);
    sx[a] = x; sy[a] = y; sz[a] = z;
    sq[a] = (x*x + y*y) + z*z;           // psq, identical arithmetic
  }
  __syncthreads();
  const int a0 = lane * 65;              // BPAD(lane*64)
#pragma unroll 1
  for (int r = 0; r < 4; ++r) {
    const int s = c0 + wave*4 + r;
    const size_t co = ((size_t)b * NS + s) * 3;
    const float cx = centers[co], cy = centers[co+1], cz = centers[co+2];
    const float csq = (cx*cx + cy*cy) + cz*cz;
    unsigned long long mask = 0ull;
#pragma unroll 8
    for (int j = 0; j < 64; ++j) {
      const float dot = (cx*sx[a0+j] + cy*sy[a0+j]) + cz*sz[a0+j];
      const float dist = (csq + sq[a0+j]) - 2.0f*dot;
      mask |= ((unsigned long long)(dist <= 0.25f)) << j;
    }
    int cnt = __popcll(mask);
    // exclusive prefix sum over lanes
    int inc = cnt;
#pragma unroll
    for (int m = 1; m < 64; m <<= 1) {
      int o = __shfl_up(inc, m);
      if (lane >= m) inc += o;
    }
    const int pre = inc - cnt;
    const int total = __shfl(inc, 63);
    // first global match (guaranteed to exist)
    unsigned long long bal = __ballot(cnt > 0);
    int fl = __ffsll(bal) - 1;
    int myfirst = cnt ? (lane << 6) + __ffsll(mask) - 1 : 0;
    int firstG = __shfl(myfirst, fl);
    int* out = group_idx + ((size_t)b * NS + s) * NK;
    if (pre < NK && cnt) {
      int k = pre;
      unsigned long long m2 = mask;
      while (m2 && k < NK) {
        int j = __ffsll(m2) - 1;
        out[k++] = (lane << 6) + j;
        m2 &= m2 - 1;
      }
    }
    if (total < NK) {
      for (int q2 = total + lane; q2 < NK; q2 += 64) out[q2] = firstG;
    }
  }
}

// ================================================================ prep
__global__ __launch_bounds__(256) void prep_kernel(
    const float* __restrict__ w0, const float* __restrict__ w1,
    const float* __restrict__ w2, float* __restrict__ wT)
{
  int i = blockIdx.x*256 + threadIdx.x;
  if (i < 4288) {
    int c = i >> 6, d = i & 63;
    wT[i] = w0[d*CIN0 + c];
  } else if (i < 8384) {
    int j = i - 4288; int c = j >> 6, d = j & 63;
    wT[i] = w1[d*64 + c];
  } else if (i < WT_TOTAL) {
    int j = i - 8384; int c = j >> 7, d = j & 127;
    wT[i] = w2[d*64 + c];
  }
}

// ================================================================ helpers
__device__ __forceinline__ float gelu_f(float x) {
  float z = fabsf(x) * 0.70710678118654752f;
  float t = __builtin_amdgcn_rcpf(fmaf(0.3275911f, z, 1.0f));
  float p = t * fmaf(t, fmaf(t, fmaf(t, fmaf(t, 1.061405429f, -1.453152027f),
                                     1.421413741f), -0.284496736f), 0.254829592f);
  float ex = __expf(-z*z);
  float er = fmaf(-p, ex, 1.0f);
  float se = __uint_as_float(__float_as_uint(er) | (__float_as_uint(x) & 0x80000000u));
  return 0.5f * x * (1.0f + se);
}
__device__ __forceinline__ float bf_lo(uint u) { return __uint_as_float(u << 16); }
__device__ __forceinline__ float bf_hi(uint u) { return __uint_as_float(u & 0xffff0000u); }
__device__ __forceinline__ uint bfpack(float a, float b) {
  uint ua = __float_as_uint(a), ub = __float_as_uint(b);
  ua = (ua + 0x7fffu + ((ua >> 16) & 1u)) >> 16;   // RNE on bit 16
  ub = (ub + 0x7fffu + ((ub >> 16) & 1u)) >> 16;
  return (ua & 0xffffu) | (ub << 16);
}

__device__ __forceinline__ void fmac64(float (&acc)[64], const float* wrow, float xc) {
  const float4* wp = (const float4*)wrow;
#pragma unroll
  for (int i = 0; i < 16; ++i) {
    float4 w = wp[i];
    acc[i*4+0] = fmaf(xc, w.x, acc[i*4+0]);
    acc[i*4+1] = fmaf(xc, w.y, acc[i*4+1]);
    acc[i*4+2] = fmaf(xc, w.z, acc[i*4+2]);
    acc[i*4+3] = fmaf(xc, w.w, acc[i*4+3]);
  }
}
__device__ __forceinline__ void fmac128(float (&acc)[128], const float* wrow, float xc) {
  const float4* wp = (const float4*)wrow;
#pragma unroll
  for (int i = 0; i < 32; ++i) {
    float4 w = wp[i];
    acc[i*4+0] = fmaf(xc, w.x, acc[i*4+0]);
    acc[i*4+1] = fmaf(xc, w.y, acc[i*4+1]);
    acc[i*4+2] = fmaf(xc, w.z, acc[i*4+2]);
    acc[i*4+3] = fmaf(xc, w.w, acc[i*4+3]);
  }
}

// layer0 for point p into acc[64]; wsh = W0T [67][64] in LDS; b0v in LDS.
__device__ __forceinline__ void layer0(
    const float* __restrict__ xyz, const float* __restrict__ feat,
    const float* __restrict__ centers, const int* __restrict__ gidx,
    const float* wsh, const float* b0v, int p, float (&acc)[64])
{
  const int b = p >> 15;
  const int s = (p & 32767) >> 5;
  const int gi = gidx[p];
#pragma unroll
  for (int d = 0; d < 64; ++d) acc[d] = b0v[d];
  const float* cp = centers + ((size_t)(b*NS + s))*3;
  const float* pp = xyz + ((size_t)(b*NN) + gi)*3;
  const float4* fr = (const float4*)(feat + ((size_t)(b*NN) + gi)*64);
  float4 f = fr[0];
  fmac64(acc, wsh + 0*64, pp[0]-cp[0]);
  fmac64(acc, wsh + 1*64, pp[1]-cp[1]);
  fmac64(acc, wsh + 2*64, pp[2]-cp[2]);
#pragma unroll 1
  for (int q = 0; q < 16; ++q) {
    const int nq = (q < 15) ? q + 1 : 15;
    float4 fn = fr[nq];
    fmac64(acc, wsh + (3+q*4)*64, f.x);
    fmac64(acc, wsh + (4+q*4)*64, f.y);
    fmac64(acc, wsh + (5+q*4)*64, f.z);
    fmac64(acc, wsh + (6+q*4)*64, f.w);
    f = fn;
  }
}

// per-channel block column-sums of v into bsum/bssq
__device__ __forceinline__ void block_colsum64(const float (&v)[64], float* sbuf,
    float* bsum, float* bssq, int cbase)
{
  const int tid = threadIdx.x;
#pragma unroll
  for (int cc = 0; cc < 4; ++cc) {
    __syncthreads();
#pragma unroll
    for (int j = 0; j < 16; ++j) sbuf[tid*17 + j] = v[cc*16 + j];
    __syncthreads();
    const int c = tid & 15, seg = tid >> 4;
    float s = 0.f, q = 0.f;
#pragma unroll
    for (int i = 0; i < 16; ++i) {
      float x = sbuf[(seg*16 + i)*17 + c];
      s += x; q += x*x;
    }
    __syncthreads();
    sbuf[tid*2] = s; sbuf[tid*2+1] = q;
    __syncthreads();
    if (tid < 16) {
      float ss = 0.f, qq = 0.f;
#pragma unroll
      for (int sg = 0; sg < 16; ++sg) {
        ss += sbuf[(sg*16 + tid)*2];
        qq += sbuf[(sg*16 + tid)*2 + 1];
      }
      bsum[cbase + cc*16 + tid] += ss;
      bssq[cbase + cc*16 + tid] += qq;
    }
  }
  __syncthreads();
}

// ================================================================ tiered pipeline
__global__ __launch_bounds__(256,3) void p0_kernel(
    const float* __restrict__ xyz, const float* __restrict__ feat,
    const float* __restrict__ centers, const int* __restrict__ gidx,
    const float* __restrict__ wT, const float* __restrict__ b0,
    ushort* __restrict__ X, float* __restrict__ stat0)
{
  __shared__ float wsh[4288];
  __shared__ float sbuf[4352];
  __shared__ float bsum[64], bssq[64], b0s[64];
  const int tid = threadIdx.x;
  for (int i = tid; i < 1072; i += 256) ((float4*)wsh)[i] = ((const float4*)wT)[i];
  if (tid < 64) { bsum[tid] = 0.f; bssq[tid] = 0.f; b0s[tid] = b0[tid]; }
  __syncthreads();
  const int p = blockIdx.x*256 + tid;
  float acc[64];
  layer0(xyz, feat, centers, gidx, wsh, b0s, p, acc);
  uint4* xr = (uint4*)(X + (size_t)p*64);
#pragma unroll
  for (int q = 0; q < 8; ++q) {
    uint4 pk;
    pk.x = bfpack(acc[q*8+0], acc[q*8+1]);
    pk.y = bfpack(acc[q*8+2], acc[q*8+3]);
    pk.z = bfpack(acc[q*8+4], acc[q*8+5]);
    pk.w = bfpack(acc[q*8+6], acc[q*8+7]);
    xr[q] = pk;
  }
  block_colsum64(acc, sbuf, bsum, bssq, 0);
  if (tid < 64) {
    atomicAdd(&stat0[tid], bsum[tid]);
    atomicAdd(&stat0[64+tid], bssq[tid]);
  }
}

__global__ __launch_bounds__(256,3) void p1_kernel(
    ushort* X, const float* __restrict__ wT,
    const float* __restrict__ stat0, const float* __restrict__ g0,
    const float* __restrict__ be0, const float* __restrict__ b1,
    float* __restrict__ stat1)
{
  __shared__ float wsh[4096];   // W1T
  __shared__ float sbuf[4352];
  __shared__ float bsum[64], bssq[64];
  __shared__ float sc[64], sh[64], b1s[64];
  const int tid = threadIdx.x;
  for (int i = tid; i < 1024; i += 256)
    ((float4*)wsh)[i] = ((const float4*)(wT + W1T_OFF))[i];
  if (tid < 64) {
    float m0 = stat0[tid]*INV_NPTS;
    float v0 = stat0[64+tid]*INV_NPTS - m0*m0;
    float s0 = (1.0f/sqrtf(v0 + BN_EPS)) * g0[tid];
    sc[tid] = s0; sh[tid] = be0[tid] - m0*s0;
    b1s[tid] = b1[tid];
    bsum[tid] = 0.f; bssq[tid] = 0.f;
  }
  __syncthreads();
  const int p = blockIdx.x*256 + tid;
  uint4* xr = (uint4*)(X + (size_t)p*64);
  float acc[64];
#pragma unroll
  for (int d = 0; d < 64; ++d) acc[d] = b1s[d];
  uint4 v = xr[0];
#pragma unroll 1
  for (int ch = 0; ch < 8; ++ch) {
    const int nc = (ch < 7) ? ch + 1 : 7;
    uint4 vn = xr[nc];
    const int c = ch*8;
    float x0 = gelu_f(fmaf(bf_lo(v.x), sc[c+0], sh[c+0]));
    float x1 = gelu_f(fmaf(bf_hi(v.x), sc[c+1], sh[c+1]));
    float x2 = gelu_f(fmaf(bf_lo(v.y), sc[c+2], sh[c+2]));
    float x3 = gelu_f(fmaf(bf_hi(v.y), sc[c+3], sh[c+3]));
    float x4 = gelu_f(fmaf(bf_lo(v.z), sc[c+4], sh[c+4]));
    float x5 = gelu_f(fmaf(bf_hi(v.z), sc[c+5], sh[c+5]));
    float x6 = gelu_f(fmaf(bf_lo(v.w), sc[c+6], sh[c+6]));
    float x7 = gelu_f(fmaf(bf_hi(v.w), sc[c+7], sh[c+7]));
    fmac64(acc, wsh + (c+0)*64, x0);
    fmac64(acc, wsh + (c+1)*64, x1);
    fmac64(acc, wsh + (c+2)*64, x2);
    fmac64(acc, wsh + (c+3)*64, x3);
    fmac64(acc, wsh + (c+4)*64, x4);
    fmac64(acc, wsh + (c+5)*64, x5);
    fmac64(acc, wsh + (c+6)*64, x6);
    fmac64(acc, wsh + (c+7)*64, x7);
    v = vn;
  }
#pragma unroll
  for (int q = 0; q < 8; ++q) {
    uint4 pk;
    pk.x = bfpack(acc[q*8+0], acc[q*8+1]);
    pk.y = bfpack(acc[q*8+2], acc[q*8+3]);
    pk.z = bfpack(acc[q*8+4], acc[q*8+5]);
    pk.w = bfpack(acc[q*8+6], acc[q*8+7]);
    xr[q] = pk;
  }
  block_colsum64(acc, sbuf, bsum, bssq, 0);
  if (tid < 64) {
    atomicAdd(&stat1[tid], bsum[tid]);
    atomicAdd(&stat1[64+tid], bssq[tid]);
  }
}

template<bool STORE_H2>
__global__ __launch_bounds__(256,2) void p2_kernel(
    ushort* X, ushort* __restrict__ H2, const float* __restrict__ wT,
    const float* __restrict__ stat1, const float* __restrict__ g1,
    const float* __restrict__ be1, const float* __restrict__ b2,
    float* __restrict__ stat2)
{
  __shared__ float wsh[8192];   // W2T [64][128]
  __shared__ float sbuf[4352];
  __shared__ float bsum[128], bssq[128];
  __shared__ float sc[64], sh[64], b2s[128];
  const int tid = threadIdx.x;
  for (int i = tid; i < 2048; i += 256)
    ((float4*)wsh)[i] = ((const float4*)(wT + W2T_OFF))[i];
  if (tid < 64) {
    float m1 = stat1[tid]*INV_NPTS;
    float v1 = stat1[64+tid]*INV_NPTS - m1*m1;
    float s1 = (1.0f/sqrtf(v1 + BN_EPS)) * g1[tid];
    sc[tid] = s1; sh[tid] = be1[tid] - m1*s1;
  }
  if (tid < 128) { b2s[tid] = b2[tid]; bsum[tid] = 0.f; bssq[tid] = 0.f; }
  __syncthreads();
  const int p = blockIdx.x*256 + tid;
  uint4* xr = (uint4*)(X + (size_t)p*64);
  float acc[128];
#pragma unroll
  for (int d = 0; d < 128; ++d) acc[d] = b2s[d];
  uint4 v = xr[0];
#pragma unroll 1
  for (int ch = 0; ch < 8; ++ch) {
    const int nc = (ch < 7) ? ch + 1 : 7;
    uint4 vn = xr[nc];
    const int c = ch*8;
    float x0 = gelu_f(fmaf(bf_lo(v.x), sc[c+0], sh[c+0]));
    float x1 = gelu_f(fmaf(bf_hi(v.x), sc[c+1], sh[c+1]));
    float x2 = gelu_f(fmaf(bf_lo(v.y), sc[c+2], sh[c+2]));
    float x3 = gelu_f(fmaf(bf_hi(v.y), sc[c+3], sh[c+3]));
    float x4 = gelu_f(fmaf(bf_lo(v.z), sc[c+4], sh[c+4]));
    float x5 = gelu_f(fmaf(bf_hi(v.z), sc[c+5], sh[c+5]));
    float x6 = gelu_f(fmaf(bf_lo(v.w), sc[c+6], sh[c+6]));
    float x7 = gelu_f(fmaf(bf_hi(v.w), sc[c+7], sh[c+7]));
    if (!STORE_H2) {
      uint4 pk;
      pk.x = bfpack(x0, x1); pk.y = bfpack(x2, x3);
      pk.z = bfpack(x4, x5); pk.w = bfpack(x6, x7);
      xr[ch] = pk;
    }
    fmac128(acc, wsh + (c+0)*128, x0);
    fmac128(acc, wsh + (c+1)*128, x1);
    fmac128(acc, wsh + (c+2)*128, x2);
    fmac128(acc, wsh + (c+3)*128, x3);
    fmac128(acc, wsh + (c+4)*128, x4);
    fmac128(acc, wsh + (c+5)*128, x5);
    fmac128(acc, wsh + (c+6)*128, x6);
    fmac128(acc, wsh + (c+7)*128, x7);
    v = vn;
  }
  if (STORE_H2) {
    uint4* hr = (uint4*)(H2 + (size_t)p*128);
#pragma unroll
    for (int q = 0; q < 16; ++q) {
      uint4 pk;
      pk.x = bfpack(acc[q*8+0], acc[q*8+1]);
      pk.y = bfpack(acc[q*8+2], acc[q*8+3]);
      pk.z = bfpack(acc[q*8+4], acc[q*8+5]);
      pk.w = bfpack(acc[q*8+6], acc[q*8+7]);
      hr[q] = pk;
    }
  }
#pragma unroll
  for (int half = 0; half < 2; ++half) {
    float tmp[64];
#pragma unroll
    for (int d = 0; d < 64; ++d) tmp[d] = acc[half*64 + d];
    block_colsum64(tmp, sbuf, bsum, bssq, half*64);
  }
  if (tid < 128) {
    atomicAdd(&stat2[tid], bsum[tid]);
    atomicAdd(&stat2[128+tid], bssq[tid]);
  }
}

__global__ __launch_bounds__(128) void fbig_kernel(
    const ushort* __restrict__ H2, const float* __restrict__ stat2,
    const float* __restrict__ g2, const float* __restrict__ be2,
    float* __restrict__ out_feat)
{
  const int d = threadIdx.x;
  const int bs = blockIdx.x;
  const float mean = stat2[d] * INV_NPTS;
  const float var  = stat2[128+d] * INV_NPTS - mean*mean;
  const float scale = (1.0f/sqrtf(var + BN_EPS)) * g2[d];
  const float shift = be2[d] - mean*scale;
  const ushort* rp = H2 + (size_t)bs*NK*128 + d;
  float m = -3.4e38f;
#pragma unroll 4
  for (int k = 0; k < NK; ++k) {
    float t = __uint_as_float(((uint)rp[k*128]) << 16);
    m = fmaxf(m, gelu_f(fmaf(t, scale, shift)));
  }
  out_feat[(size_t)bs*128 + d] = m;
}

__global__ __launch_bounds__(256,2) void fsmall_kernel(
    const ushort* __restrict__ X, const float* __restrict__ wT,
    const float* __restrict__ b2, const float* __restrict__ stat2,
    const float* __restrict__ g2, const float* __restrict__ be2,
    float* __restrict__ out_feat)
{
  __shared__ float wsh[8192];
  __shared__ float b2s[128], sc2[128], sh2[128];
  const int tid = threadIdx.x;
  for (int i = tid; i < 2048; i += 256)
    ((float4*)wsh)[i] = ((const float4*)(wT + W2T_OFF))[i];
  if (tid < 128) {
    b2s[tid] = b2[tid];
    float m2 = stat2[tid]*INV_NPTS;
    float v2 = stat2[128+tid]*INV_NPTS - m2*m2;
    float s2 = (1.0f/sqrtf(v2 + BN_EPS)) * g2[tid];
    sc2[tid] = s2; sh2[tid] = be2[tid] - m2*s2;
  }
  __syncthreads();
  const int p = blockIdx.x*256 + tid;
  const int bs = p >> 5;
  const uint4* xr = (const uint4*)(X + (size_t)p*64);
  float acc[128];
#pragma unroll
  for (int d = 0; d < 128; ++d) acc[d] = b2s[d];
  uint4 v = xr[0];
#pragma unroll 1
  for (int ch = 0; ch < 8; ++ch) {
    const int nc = (ch < 7) ? ch + 1 : 7;
    uint4 vn = xr[nc];
    const int c = ch*8;
    fmac128(acc, wsh + (c+0)*128, bf_lo(v.x));
    fmac128(acc, wsh + (c+1)*128, bf_hi(v.x));
    fmac128(acc, wsh + (c+2)*128, bf_lo(v.y));
    fmac128(acc, wsh + (c+3)*128, bf_hi(v.y));
    fmac128(acc, wsh + (c+4)*128, bf_lo(v.z));
    fmac128(acc, wsh + (c+5)*128, bf_hi(v.z));
    fmac128(acc, wsh + (c+6)*128, bf_lo(v.w));
    fmac128(acc, wsh + (c+7)*128, bf_hi(v.w));
    v = vn;
  }
#pragma unroll
  for (int d = 0; d < 128; ++d) {
    float y = gelu_f(fmaf(acc[d], sc2[d], sh2[d]));
#pragma unroll
    for (int m = 1; m < 32; m <<= 1) y = fmaxf(y, __shfl_xor(y, m));
    acc[d] = y;
  }
  if ((tid & 31) == 0) {
    float4* op = (float4*)(out_feat + (size_t)bs*128);
#pragma unroll
    for (int i = 0; i < 32; ++i)
      op[i] = make_float4(acc[i*4], acc[i*4+1], acc[i*4+2], acc[i*4+3]);
  }
}

// ================================================================ fallback (recompute path)
__device__ __forceinline__ void chain_to_x2(
    const float* __restrict__ xyz, const float* __restrict__ feat,
    const float* __restrict__ centers, const int* __restrict__ gidx,
    const float* wsh, float* sbuf, const float* prm, int p, float (&x2)[64])
{
  float acc0[64];
  layer0(xyz, feat, centers, gidx, wsh, prm, p, acc0);
#pragma unroll
  for (int c = 0; c < 64; ++c) acc0[c] = gelu_f(fmaf(acc0[c], prm[64+c], prm[128+c]));
#pragma unroll
  for (int d = 0; d < 64; ++d) x2[d] = prm[192+d];
  float* xrow = sbuf + threadIdx.x*17;
#pragma unroll
  for (int cc = 0; cc < 4; ++cc) {
#pragma unroll
    for (int j = 0; j < 16; ++j) xrow[j] = acc0[cc*16 + j];
#pragma unroll 1
    for (int cj = 0; cj < 16; ++cj)
      fmac64(x2, wsh + W1T_OFF + (cc*16+cj)*64, xrow[cj]);
  }
#pragma unroll
  for (int c = 0; c < 64; ++c) x2[c] = gelu_f(fmaf(x2[c], prm[256+c], prm[320+c]));
}

__global__ __launch_bounds__(256,2) void s0_kernel(
    const float* __restrict__ xyz, const float* __restrict__ feat,
    const float* __restrict__ centers, const int* __restrict__ gidx,
    const float* __restrict__ wT, const float* __restrict__ b0,
    float* __restrict__ stat0)
{
  __shared__ float wsh[4288];
  __shared__ float sbuf[4352];
  __shared__ float bsum[64], bssq[64], b0s[64];
  const int tid = threadIdx.x;
  for (int i = tid; i < 1072; i += 256) ((float4*)wsh)[i] = ((const float4*)wT)[i];
  if (tid < 64) { bsum[tid] = 0.f; bssq[tid] = 0.f; b0s[tid] = b0[tid]; }
  __syncthreads();
  const int p = blockIdx.x*256 + tid;
  float acc[64];
  layer0(xyz, feat, centers, gidx, wsh, b0s, p, acc);
  block_colsum64(acc, sbuf, bsum, bssq, 0);
  if (tid < 64) {
    atomicAdd(&stat0[tid], bsum[tid]);
    atomicAdd(&stat0[64+tid], bssq[tid]);
  }
}

__global__ __launch_bounds__(256,2) void s1_kernel(
    const float* __restrict__ xyz, const float* __restrict__ feat,
    const float* __restrict__ centers, const int* __restrict__ gidx,
    const float* __restrict__ wT, const float* __restrict__ stat0,
    const float* __restrict__ g0, const float* __restrict__ be0,
    const float* __restrict__ b0, const float* __restrict__ b1,
    float* __restrict__ stat1)
{
  __shared__ float wsh[8384];
  __shared__ float sbuf[4352];
  __shared__ float bsum[64], bssq[64];
  __shared__ float prm[256];
  const int tid = threadIdx.x;
  for (int i = tid; i < 2096; i += 256) ((float4*)wsh)[i] = ((const float4*)wT)[i];
  if (tid < 64) {
    float m0 = stat0[tid]*INV_NPTS;
    float v0 = stat0[64+tid]*INV_NPTS - m0*m0;
    float sc0 = (1.0f/sqrtf(v0 + BN_EPS)) * g0[tid];
    prm[tid] = b0[tid]; prm[64+tid] = sc0; prm[128+tid] = be0[tid] - m0*sc0;
    prm[192+tid] = b1[tid];
    bsum[tid] = 0.f; bssq[tid] = 0.f;
  }
  __syncthreads();
  const int p = blockIdx.x*256 + tid;
  float acc0[64];
  layer0(xyz, feat, centers, gidx, wsh, prm, p, acc0);
#pragma unroll
  for (int c = 0; c < 64; ++c) acc0[c] = gelu_f(fmaf(acc0[c], prm[64+c], prm[128+c]));
  float acc1[64];
#pragma unroll
  for (int d = 0; d < 64; ++d) acc1[d] = prm[192+d];
  float* xrow = sbuf + tid*17;
#pragma unroll
  for (int cc = 0; cc < 4; ++cc) {
#pragma unroll
    for (int j = 0; j < 16; ++j) xrow[j] = acc0[cc*16 + j];
#pragma unroll 1
    for (int cj = 0; cj < 16; ++cj)
      fmac64(acc1, wsh + W1T_OFF + (cc*16+cj)*64, xrow[cj]);
  }
  block_colsum64(acc1, sbuf, bsum, bssq, 0);
  if (tid < 64) {
    atomicAdd(&stat1[tid], bsum[tid]);
    atomicAdd(&stat1[64+tid], bssq[tid]);
  }
}

__global__ __launch_bounds__(256,2) void s2_kernel(
    const float* __restrict__ xyz, const float* __restrict__ feat,
    const float* __restrict__ centers, const int* __restrict__ gidx,
    const float* __restrict__ wT,
    const float* __restrict__ stat0, const float* __restrict__ g0,
    const float* __restrict__ be0, const float* __restrict__ b0,
    const float* __restrict__ b1, const float* __restrict__ stat1,
    const float* __restrict__ g1, const float* __restrict__ be1,
    const float* __restrict__ b2, float* __restrict__ stat2)
{
  __shared__ float wsh[8384];
  __shared__ float sbuf[4352];
  __shared__ float bsum[128], bssq[128];
  __shared__ float prm[512];
  const int tid = threadIdx.x;
  for (int i = tid; i < 2096; i += 256) ((float4*)wsh)[i] = ((const float4*)wT)[i];
  if (tid < 64) {
    float m0 = stat0[tid]*INV_NPTS;
    float v0 = stat0[64+tid]*INV_NPTS - m0*m0;
    float sc0 = (1.0f/sqrtf(v0 + BN_EPS)) * g0[tid];
    prm[tid] = b0[tid]; prm[64+tid] = sc0; prm[128+tid] = be0[tid] - m0*sc0;
    float m1 = stat1[tid]*INV_NPTS;
    float v1 = stat1[64+tid]*INV_NPTS - m1*m1;
    float sc1 = (1.0f/sqrtf(v1 + BN_EPS)) * g1[tid];
    prm[192+tid] = b1[tid]; prm[256+tid] = sc1; prm[320+tid] = be1[tid] - m1*sc1;
  }
  if (tid < 128) { prm[384+tid] = b2[tid]; bsum[tid] = 0.f; bssq[tid] = 0.f; }
  __syncthreads();
  const int p = blockIdx.x*256 + tid;
  float x2[64];
  chain_to_x2(xyz, feat, centers, gidx, wsh, sbuf, prm, p, x2);
  __syncthreads();
  for (int i = tid; i < 2048; i += 256)
    ((float4*)wsh)[i] = ((const float4*)(wT + W2T_OFF))[i];
  __syncthreads();
  float* xrow = sbuf + tid*17;
#pragma unroll 1
  for (int half = 0; half < 2; ++half) {
    float a2[64];
#pragma unroll
    for (int d = 0; d < 64; ++d) a2[d] = prm[384 + half*64 + d];
#pragma unroll
    for (int cc = 0; cc < 4; ++cc) {
#pragma unroll
      for (int j = 0; j < 16; ++j) xrow[j] = x2[cc*16 + j];
#pragma unroll 1
      for (int cj = 0; cj < 16; ++cj)
        fmac64(a2, wsh + (cc*16+cj)*128 + half*64, xrow[cj]);
    }
    block_colsum64(a2, sbuf, bsum, bssq, half*64);
  }
  if (tid < 128) {
    atomicAdd(&stat2[tid], bsum[tid]);
    atomicAdd(&stat2[128+tid], bssq[tid]);
  }
}

__global__ __launch_bounds__(256,2) void fin_kernel(
    const float* __restrict__ xyz, const float* __restrict__ feat,
    const float* __restrict__ centers, const int* __restrict__ gidx,
    const float* __restrict__ wT,
    const float* __restrict__ stat0, const float* __restrict__ g0,
    const float* __restrict__ be0, const float* __restrict__ b0,
    const float* __restrict__ b1, const float* __restrict__ stat1,
    const float* __restrict__ g1, const float* __restrict__ be1,
    const float* __restrict__ b2, const float* __restrict__ stat2,
    const float* __restrict__ g2, const float* __restrict__ be2,
    float* __restrict__ out_feat)
{
  __shared__ float wsh[8384];
  __shared__ float sbuf[4352];
  __shared__ float prm[768];
  const int tid = threadIdx.x;
  for (int i = tid; i < 2096; i += 256) ((float4*)wsh)[i] = ((const float4*)wT)[i];
  if (tid < 64) {
    float m0 = stat0[tid]*INV_NPTS;
    float v0 = stat0[64+tid]*INV_NPTS - m0*m0;
    float sc0 = (1.0f/sqrtf(v0 + BN_EPS)) * g0[tid];
    prm[tid] = b0[tid]; prm[64+tid] = sc0; prm[128+tid] = be0[tid] - m0*sc0;
    float m1 = stat1[tid]*INV_NPTS;
    float v1 = stat1[64+tid]*INV_NPTS - m1*m1;
    float sc1 = (1.0f/sqrtf(v1 + BN_EPS)) * g1[tid];
    prm[192+tid] = b1[tid]; prm[256+tid] = sc1; prm[320+tid] = be1[tid] - m1*sc1;
  }
  if (tid < 128) {
    prm[384+tid] = b2[tid];
    float m2 = stat2[tid]*INV_NPTS;
    float v2 = stat2[128+tid]*INV_NPTS - m2*m2;
    float sc2 = (1.0f/sqrtf(v2 + BN_EPS)) * g2[tid];
    prm[512+tid] = sc2; prm[640+tid] = be2[tid] - m2*sc2;
  }
  __syncthreads();
  const int p = blockIdx.x*256 + tid;
  const int b = p >> 15;
  const int s = (p & 32767) >> 5;
  float x2[64];
  chain_to_x2(xyz, feat, centers, gidx, wsh, sbuf, prm, p, x2);
  __syncthreads();
  for (int i = tid; i < 2048; i += 256)
    ((float4*)wsh)[i] = ((const float4*)(wT + W2T_OFF))[i];
  __syncthreads();
  float* xrow = sbuf + tid*17;
#pragma unroll 1
  for (int half = 0; half < 2; ++half) {
    float a2[64];
#pragma unroll
    for (int d = 0; d < 64; ++d) a2[d] = prm[384 + half*64 + d];
#pragma unroll
    for (int cc = 0; cc < 4; ++cc) {
#pragma unroll
      for (int j = 0; j < 16; ++j) xrow[j] = x2[cc*16 + j];
#pragma unroll 1
      for (int cj = 0; cj < 16; ++cj)
        fmac64(a2, wsh + (cc*16+cj)*128 + half*64, xrow[cj]);
    }
#pragma unroll
    for (int d = 0; d < 64; ++d) {
      float y = gelu_f(fmaf(a2[d], prm[512 + half*64 + d], prm[640 + half*64 + d]));
#pragma unroll
      for (int m = 1; m < 32; m <<= 1) y = fmaxf(y, __shfl_xor(y, m));
      a2[d] = y;
    }
    if ((tid & 31) == 0) {
      float4* op = (float4*)(out_feat + ((size_t)(b*NS + s))*128 + half*64);
#pragma unroll
      for (int i = 0; i < 16; ++i)
        op[i] = make_float4(a2[i*4], a2[i*4+1], a2[i*4+2], a2[i*4+3]);
    }
  }
}

// ================================================================ launch
extern "C" void kernel_launch(void* const* d_in, const int* in_sizes, int n_in,
                              void* d_out, int out_size, void* d_ws, size_t ws_size,
                              hipStream_t stream) {
  (void)in_sizes; (void)n_in; (void)out_size;
  const float* xyz      = (const float*)d_in[0];
  const float* features = (const float*)d_in[1];
  const float* w0  = (const float*)d_in[2];
  const float* b0  = (const float*)d_in[3];
  const float* g0  = (const float*)d_in[4];
  const float* be0 = (const float*)d_in[5];
  const float* w1  = (const float*)d_in[6];
  const float* b1  = (const float*)d_in[7];
  const float* g1  = (const float*)d_in[8];
  const float* be1 = (const float*)d_in[9];
  const float* w2  = (const float*)d_in[10];
  const float* b2  = (const float*)d_in[11];
  const float* g2  = (const float*)d_in[12];
  const float* be2 = (const float*)d_in[13];

  float* out = (float*)d_out;
  float* out_newxyz = out;                 // (16,1024,3)
  float* out_feat   = out + NB*NS*3;       // (16,1024,128)

  char* ws = (char*)d_ws;
  size_t off = 0;
  float* centers   = (float*)(ws + off); off += (size_t)NB*NS*3*4;
  int*   group_idx = (int*)(ws + off);   off += (size_t)NPTS*4;
  float* stats     = (float*)(ws + off); off += 512*4;
  off = (off + 255) & ~(size_t)255;
  float* wT        = (float*)(ws + off); off += (size_t)WT_TOTAL*4;
  off = (off + 255) & ~(size_t)255;
  const size_t base_end = off;
  const size_t X_bytes  = (size_t)NPTS*64*2;   // 67.1 MB
  const size_t H2_bytes = (size_t)NPTS*128*2;  // 134.2 MB
  ushort* X  = (ushort*)(ws + base_end);
  ushort* H2 = (ushort*)(ws + base_end + X_bytes);

  const bool tier_big   = ws_size >= base_end + X_bytes + H2_bytes;
  const bool tier_small = !tier_big && ws_size >= base_end + X_bytes;
  if (ws_size < base_end) return;

  float* stat0 = stats;
  float* stat1 = stats + 128;
  float* stat2 = stats + 256;

  (void)hipMemsetAsync(stats, 0, 2048, stream);
  prep_kernel<<<65, 256, 0, stream>>>(w0, w1, w2, wT);
  fps_kernel<<<NB, FPS_T, 0, stream>>>(xyz, centers, out_newxyz);
  ball_kernel<<<NB*64, 256, 0, stream>>>(xyz, centers, group_idx);

  if (tier_big || tier_small) {
    p0_kernel<<<NPTS/256, 256, 0, stream>>>(xyz, features, centers, group_idx,
                                            wT, b0, X, stat0);
    p1_kernel<<<NPTS/256, 256, 0, stream>>>(X, wT, stat0, g0, be0, b1, stat1);
    if (tier_big) {
      p2_kernel<true><<<NPTS/256, 256, 0, stream>>>(X, H2, wT, stat1, g1, be1, b2, stat2);
      fbig_kernel<<<NB*NS, 128, 0, stream>>>(H2, stat2, g2, be2, out_feat);
    } else {
      p2_kernel<false><<<NPTS/256, 256, 0, stream>>>(X, H2, wT, stat1, g1, be1, b2, stat2);
      fsmall_kernel<<<NPTS/256, 256, 0, stream>>>(X, wT, b2, stat2, g2, be2, out_feat);
    }
  } else {
    s0_kernel<<<NPTS/256, 256, 0, stream>>>(xyz, features, centers, group_idx, wT, b0, stat0);
    s1_kernel<<<NPTS/256, 256, 0, stream>>>(xyz, features, centers, group_idx, wT,
                                            stat0, g0, be0, b0, b1, stat1);
    s2_kernel<<<NPTS/256, 256, 0, stream>>>(xyz, features, centers, group_idx, wT,
                                            stat0, g0, be0, b0, b1, stat1, g1, be1, b2, stat2);
    fin_kernel<<<NPTS/256, 256, 0, stream>>>(xyz, features, centers, group_idx, wT,
                                             stat0, g0, be0, b0, b1, stat1, g1, be1, b2,
                                             stat2, g2, be2, out_feat);
  }
}